// Round 8
// baseline (545.323 us; speedup 1.0000x reference)
//
#include <hip/hip_runtime.h>

// SOMNetwork forward. All four rbf/cdist layers via split-bf16 MFMA GEMM
// (hi/lo decomposition, 3 MFMAs/product).
// Round 17: L4 coop fusion REVERTED (r7: grid.sync skew cost ~40us > 18us BW
// saved; K-loop MFMA-busy time was identical). Back to r5 dataflow.
// NEW: gemm_dist_pipe epilogue stores via LDS transpose -> coalesced float4
// (was 128 scattered dwords/thread = 64B granules + partial-line fills).
// dist leading dims padded to 240/640/1232 so every store is 16B-aligned;
// d^2 values and s/q reduction FP order are bitwise-unchanged.
// L1: d1 materialization; l1_gemm_d2 (LDS-transpose s/q reduce + cvt_pk
// hi/lo split) + l1_sfm_lite BW-bound re-read.
// L2/L3/L4 GEMM: 256x256-tile 8-wave 4-phase counted-vmcnt schedule (r14).
// prep_all merges zero_acc + 4x w_prep. Channels batched into grid z.

typedef unsigned short u16;
typedef short bf16x8 __attribute__((ext_vector_type(8)));
typedef float f32x4 __attribute__((ext_vector_type(4)));
typedef unsigned int u32;
typedef u32 u32x4 __attribute__((ext_vector_type(4)));

#define STRIPES 64
#define ACC_L2 0            // 64 stripes * 2 doubles per layer region
#define ACC_L3 128
#define ACC_L4 256
#define ACC_TOTAL 384

__device__ __forceinline__ u16 f2bf(float f) {
  unsigned int u = __float_as_uint(f);
  unsigned int r = (u + 0x7fffu + ((u >> 16) & 1u)) >> 16;
  return (u16)r;
}
__device__ __forceinline__ float bf2f(u16 h) {
  return __uint_as_float(((unsigned int)h) << 16);
}
// packed RNE bf16 convert: low16 = bf16(a), high16 = bf16(b)
__device__ __forceinline__ u32 cvtpk_bf16(float a, float b) {
  u32 r;
  asm("v_cvt_pk_bf16_f32 %0, %1, %2" : "=v"(r) : "v"(a), "v"(b));
  return r;
}
__device__ __forceinline__ float fexp(float x) { return __expf(x); }
__device__ __forceinline__ float fsqrt(float x) { return __builtin_amdgcn_sqrtf(x); }
__device__ __forceinline__ void gload16(const void* g, const void* l) {
  __builtin_amdgcn_global_load_lds(
      (const __attribute__((address_space(1))) unsigned int*)g,
      (__attribute__((address_space(3))) unsigned int*)l, 16, 0, 0);
}

// ---------------- prep_all: zero acc + all four w_preps in one dispatch ----------------
// block map: [0,9) zero acc; then L1 384, L2 768, L3 2304, L4 3840 blocks.
__global__ __launch_bounds__(128) void prep_all(
    const float* __restrict__ w1, const float* __restrict__ w2,
    const float* __restrict__ w3, const float* __restrict__ w4,
    u16* __restrict__ W1h, u16* __restrict__ W1l,
    u16* __restrict__ Whi2, u16* __restrict__ Wlo2,
    u16* __restrict__ Whi3, u16* __restrict__ Wlo3,
    u16* __restrict__ Whi4, u16* __restrict__ Wlo4,
    float* __restrict__ w1n, float* __restrict__ wn2,
    float* __restrict__ wn3, float* __restrict__ wn4,
    double* __restrict__ accd, int naccd)
{
  __shared__ float red[2];
  int bid = blockIdx.x, t = threadIdx.x;
  if (bid < 9) {
    int i = bid * 128 + t;
    if (i < naccd) accd[i] = 0.0;
    return;
  }
  bid -= 9;
  const float* W; u16 *hi, *lo; float* wn; int O, K, Opad, Kp;
  if (bid < 384)        { W = w1; hi = W1h;  lo = W1l;  wn = w1n; O = 100;  K = 25;  Opad = 128;  Kp = 32;  }
  else if (bid < 1152)  { bid -= 384;  W = w2; hi = Whi2; lo = Wlo2; wn = wn2; O = 225;  K = 100; Opad = 256;  Kp = 128; }
  else if (bid < 3456)  { bid -= 1152; W = w3; hi = Whi3; lo = Wlo3; wn = wn3; O = 625;  K = 225; Opad = 768;  Kp = 256; }
  else                  { bid -= 3456; W = w4; hi = Whi4; lo = Wlo4; wn = wn4; O = 1225; K = 625; Opad = 1280; Kp = 640; }
  int o = bid % Opad, cc = bid / Opad;
  const float* src = W + ((size_t)cc * O + o) * K;
  u16* dh = hi + ((size_t)cc * Opad + o) * Kp;
  u16* dl = lo + ((size_t)cc * Opad + o) * Kp;
  float p = 0.f;
  for (int k = t; k < Kp; k += 128) {
    float v = (o < O && k < K) ? src[k] : 0.f;
    u16 h = f2bf(v);
    u16 l = f2bf(v - bf2f(h));
    dh[k] = h; dl[k] = l;
    p = fmaf(v, v, p);
  }
  for (int off = 32; off; off >>= 1) p += __shfl_down(p, off, 64);
  if ((t & 63) == 0) red[t >> 6] = p;
  __syncthreads();
  if (t == 0) wn[(size_t)cc * Opad + o] = red[0] + red[1];
}

// ---------------- L1 GEMM pass: fused patch extraction + MFMA + d^2 store ----------------
__global__ __launch_bounds__(256) void l1_gemm_d2(
    const float* __restrict__ x, int c0,
    const u16* __restrict__ W1h, const u16* __restrict__ W1l,
    const float* __restrict__ w1n, float* __restrict__ dist1, int sD1c,
    float* __restrict__ part, int sPartc, int NBLK)
{
  __shared__ __align__(16) u16 sm[16384];   // patches+W (32 KB) -> reused as smf[2][36][66]
  __shared__ float img[1568];
  __shared__ float pnsm[512];
  __shared__ float pnloc[128];
  const int t = threadIdx.x;
  const int w = t >> 6, lane = t & 63;
  const int b0 = blockIdx.x * 2;
  const int zi = blockIdx.y, c = c0 + zi;
  const u16* Wh = W1h + (size_t)c * 4096;
  const u16* Wl = W1l + (size_t)c * 4096;
  const float* wn = w1n + (size_t)c * 128;
  dist1 += (size_t)zi * sD1c;
  part  += (size_t)zi * sPartc;

  {
    const int kk = (w & 3) * 8;
#pragma unroll
    for (int u = 0; u < 2; ++u) {
      const size_t gb = (size_t)(u * 64 + lane) * 32 + kk;
      const int ls = ((w & 3) * 128 + u * 64) * 8;
      gload16(Wh + gb, sm + 8192 + ls);
      gload16(Wl + gb, sm + 12288 + ls);
    }
  }
#pragma unroll
  for (int im = 0; im < 2; ++im) {
    if (t < 196)
      ((float4*)(img + im * 784))[t] =
          ((const float4*)(x + ((size_t)(b0 + im) * 3 + c) * 784))[t];
  }
  __syncthreads();
  for (int s = t; s < 512; s += 256) {
    int q = s >> 7, row = s & 127;
    int im = row >> 6, pr = row & 63;
    int pi = pr / 6, pj = pr - pi * 6;
    const float* ib = img + im * 784 + pi * 4 * 28 + pj * 4;
    float v[8]; float pn = 0.f;
#pragma unroll
    for (int e = 0; e < 8; ++e) {
      int k = q * 8 + e;
      float val = 0.f;
      if (pr < 36 && k < 25) { int r = k / 5, ss = k - r * 5; val = ib[r * 28 + ss]; }
      v[e] = val; pn = fmaf(val, val, pn);
    }
    u32x4 hp, lp;
#pragma unroll
    for (int e = 0; e < 4; ++e) {
      u32 h = cvtpk_bf16(v[2 * e], v[2 * e + 1]);
      float l0 = v[2 * e]     - __uint_as_float(h << 16);
      float l1 = v[2 * e + 1] - __uint_as_float(h & 0xffff0000u);
      hp[e] = h;
      lp[e] = cvtpk_bf16(l0, l1);
    }
    *(u32x4*)(sm + (q * 128 + row) * 8) = hp;
    *(u32x4*)(sm + 4096 + (q * 128 + row) * 8) = lp;
    pnsm[s] = pn;
  }
  asm volatile("s_waitcnt vmcnt(0)" ::: "memory");
  __syncthreads();
  if (t < 128) pnloc[t] = pnsm[t] + pnsm[128 + t] + pnsm[256 + t] + pnsm[384 + t];

  const int wr = w >> 1, wc = w & 1;
  const int q4 = lane >> 4, r16 = lane & 15;
  f32x4 accv[4][4];
#pragma unroll
  for (int i = 0; i < 4; ++i)
#pragma unroll
    for (int j = 0; j < 4; ++j) accv[i][j] = (f32x4){0.f, 0.f, 0.f, 0.f};

  bf16x8 Ah[4], Al[4], Bh[4], Bl[4];
#pragma unroll
  for (int i = 0; i < 4; ++i) {
    int ao = (q4 * 128 + wr * 64 + i * 16 + r16) * 8;
    int bo = (q4 * 128 + wc * 64 + i * 16 + r16) * 8;
    Ah[i] = *(const bf16x8*)(sm + ao);
    Al[i] = *(const bf16x8*)(sm + 4096 + ao);
    Bh[i] = *(const bf16x8*)(sm + 8192 + bo);
    Bl[i] = *(const bf16x8*)(sm + 12288 + bo);
  }
#pragma unroll
  for (int j = 0; j < 4; ++j) {
#pragma unroll
    for (int i = 0; i < 4; ++i)
      accv[i][j] = __builtin_amdgcn_mfma_f32_16x16x32_bf16(Ah[i], Bh[j], accv[i][j], 0, 0, 0);
#pragma unroll
    for (int i = 0; i < 4; ++i)
      accv[i][j] = __builtin_amdgcn_mfma_f32_16x16x32_bf16(Al[i], Bh[j], accv[i][j], 0, 0, 0);
#pragma unroll
    for (int i = 0; i < 4; ++i)
      accv[i][j] = __builtin_amdgcn_mfma_f32_16x16x32_bf16(Ah[i], Bl[j], accv[i][j], 0, 0, 0);
  }
  __syncthreads();   // all fragment reads of sm done -> safe to reuse as smf

  // s/q partials via LDS transpose: smf[kind][pos][w*16+r16], stride 66.
  float* smf = (float*)sm;
  int colv[4]; float wnv[4];
#pragma unroll
  for (int j = 0; j < 4; ++j) {
    colv[j] = wc * 64 + j * 16 + r16;
    wnv[j] = (colv[j] < 100) ? wn[colv[j]] : 0.f;
  }
#pragma unroll
  for (int i = 0; i < 4; ++i) {
#pragma unroll
    for (int r = 0; r < 4; ++r) {
      int pos = i * 16 + q4 * 4 + r;
      if (pos < 36) {           // uniform within each 16-lane (r16) group
        float pn = pnloc[wr * 64 + pos];
        float* drow = dist1 + ((size_t)(b0 + wr) * 36 + pos) * 100;
        float sl = 0.f, ql = 0.f;
#pragma unroll
        for (int j = 0; j < 4; ++j) {
          if (colv[j] < 100) {
            float d2 = pn + wnv[j] - 2.f * accv[i][j][r];
            float d2c = fmaxf(d2, 0.f) + 1e-12f;
            drow[colv[j]] = d2c;
            sl += fsqrt(d2c); ql += d2c;
          }
        }
        smf[pos * 66 + w * 16 + r16] = sl;
        smf[(36 + pos) * 66 + w * 16 + r16] = ql;
      }
    }
  }
  __syncthreads();
  if (t < 72) {
    const float* row = smf + (size_t)t * 66;
    float v0 = 0.f;
#pragma unroll
    for (int k = 0; k < 64; ++k) v0 += row[k];
    part[(size_t)t * NBLK + blockIdx.x] = v0;
  }
}

// ---------------- L1 partial finish: per-block partials -> inv36 ----------------
__global__ __launch_bounds__(256) void l1_part_fin(
    const float* __restrict__ part, int sPartc, float* __restrict__ inv36, int sInvc,
    double n, int NBLK)
{
  __shared__ double sh[8];
  int pos = blockIdx.x, zi = blockIdx.y, t = threadIdx.x;
  part += (size_t)zi * sPartc; inv36 += (size_t)zi * sInvc;
  double s = 0.0, q = 0.0;
  for (int b = t; b < NBLK; b += 256) {
    s += part[(size_t)pos * NBLK + b];
    q += part[(size_t)(36 + pos) * NBLK + b];
  }
  for (int off = 32; off; off >>= 1) {
    s += __shfl_down(s, off, 64);
    q += __shfl_down(q, off, 64);
  }
  if ((t & 63) == 0) { sh[(t >> 6) * 2] = s; sh[(t >> 6) * 2 + 1] = q; }
  __syncthreads();
  if (t == 0) {
    s = sh[0] + sh[2] + sh[4] + sh[6];
    q = sh[1] + sh[3] + sh[5] + sh[7];
    double var = (q - s * s / n) / (n - 1.0);
    inv36[pos] = var > 0.0 ? (float)(0.5 / var) : __builtin_inff();
  }
}

// ---------------- L1 sfm: d^2 -> exp/crelu -> 2x2 alpha-pool -> X hi/lo + xn ----------------
__global__ __launch_bounds__(128) void l1_sfm_lite(
    const float* __restrict__ d1, int sD1c,
    const float* __restrict__ inv36, int sInvc, const float* __restrict__ cb,
    u16* __restrict__ Xhi, u16* __restrict__ Xlo, float* __restrict__ xn,
    int sXc, int sxnc)
{
  __shared__ float inv_s[36];
  __shared__ float xnsm[9][2];
  int b = blockIdx.x, zi = blockIdx.y, t = threadIdx.x;
  d1 += (size_t)zi * sD1c; inv36 += (size_t)zi * sInvc;
  Xhi += (size_t)zi * sXc; Xlo += (size_t)zi * sXc; xn += (size_t)zi * sxnc;
  if (t < 36) inv_s[t] = inv36[t];
  __syncthreads();
  const float* db = d1 + (size_t)b * 3600;
  float bias = cb[0];
  int wv = t >> 6;
#pragma unroll
  for (int IJ = 0; IJ < 9; ++IJ) {
    const int I = IJ / 3, J = IJ - I * 3;
    const int p00 = 12 * I + 2 * J;
    float v = 0.f;
    if (t < 100) {
      float e00 = fexp(-db[p00 * 100 + t] * inv_s[p00]);
      float e01 = fexp(-db[(p00 + 1) * 100 + t] * inv_s[p00 + 1]);
      float e10 = fexp(-db[(p00 + 6) * 100 + t] * inv_s[p00 + 6]);
      float e11 = fexp(-db[(p00 + 7) * 100 + t] * inv_s[p00 + 7]);
      e00 = (e00 >= bias) ? e00 : 0.f;
      e01 = (e01 >= bias) ? e01 : 0.f;
      e10 = (e10 >= bias) ? e10 : 0.f;
      e11 = (e11 >= bias) ? e11 : 0.f;
      v = 0.25f * (fmaf(0.729f, e00, 0.81f * e01) + fmaf(0.9f, e10, e11));
    }
    size_t xrow = (size_t)b * 9 + IJ;
    u16 h = f2bf(v);
    u16 l = f2bf(v - bf2f(h));
    Xhi[xrow * 128 + t] = h;
    Xlo[xrow * 128 + t] = l;
    float p = v * v;
    for (int off = 32; off; off >>= 1) p += __shfl_down(p, off, 64);
    if ((t & 63) == 0) xnsm[IJ][wv] = p;
  }
  __syncthreads();
  if (t < 9) xn[(size_t)b * 9 + t] = xnsm[t][0] + xnsm[t][1];
}

// ---------------- 256x256-tile 8-wave 4-phase pipelined split-bf16 MFMA cdist GEMM ----------------
// K-loop: 4 phases over j-pairs; stage [Xu0,Xu1,Wu0,Wu1]; waits ph0 vmcnt(2),
// ph2 vmcnt(4) (0 at last step). FP order unchanged.
// Epilogue (r17): d^2 kept in regs (s/q FP order identical), then two 128-row
// halves transposed through LDS -> fully-coalesced 16B-aligned float4 stores.
// dist leading dim Od is padded (240/640/1232); pad cols written, never read.
__global__ __launch_bounds__(512, 2) void gemm_dist_pipe(
    const u16* __restrict__ Xhi, const u16* __restrict__ Xlo,
    const u16* __restrict__ Whi, const u16* __restrict__ Wlo,
    const float* __restrict__ xn, const float* __restrict__ wn,
    float* __restrict__ dist, int O, int Od, int Kp,
    double* __restrict__ acc, int accbase, int c0,
    int sXc, int sWc, int sxnc, int swnc, int sdistc)
{
  __shared__ __align__(16) u16 sm[65536];   // 128 KB: buffers at 0 and 32768
  int zi = blockIdx.z, c = c0 + zi;
  Xhi += (size_t)zi * sXc; Xlo += (size_t)zi * sXc;
  Whi += (size_t)c * sWc;  Wlo += (size_t)c * sWc;
  xn += (size_t)zi * sxnc; wn += (size_t)c * swnc;
  dist += (size_t)zi * sdistc;
  acc += (size_t)c * ACC_TOTAL;

  const int t = threadIdx.x;
  const int w = t >> 6, lane = t & 63;
  const int wr = w >> 1, wc = w & 1;
  const int sq = w & 3, half = w >> 2;
  const int m0 = blockIdx.x * 256, o0 = blockIdx.y * 256;
  const int q4 = lane >> 4, r16 = lane & 15;
  const int nsteps = Kp / 32;

  f32x4 accv[4][8];
#pragma unroll
  for (int i = 0; i < 4; ++i)
#pragma unroll
    for (int j = 0; j < 8; ++j) accv[i][j] = (f32x4){0.f, 0.f, 0.f, 0.f};

  auto stageA_u = [&](int buf, int ks, int u) {
    const int kk = ks * 32 + sq * 8;
    u16* base = sm + buf * 32768;
    const int row = half * 128 + u * 64 + lane;
    const size_t ga = (size_t)(m0 + row) * Kp + kk;
    const int ls = (sq * 256 + half * 128 + u * 64) * 8;
    gload16(Xhi + ga, base + ls);
    gload16(Xlo + ga, base + 8192 + ls);
  };
  auto stageB_u = [&](int buf, int ks, int u) {
    const int kk = ks * 32 + sq * 8;
    u16* base = sm + buf * 32768;
    const int row = half * 128 + u * 64 + lane;
    const size_t gb = (size_t)(o0 + row) * Kp + kk;
    const int ls = (sq * 256 + half * 128 + u * 64) * 8;
    gload16(Whi + gb, base + 16384 + ls);
    gload16(Wlo + gb, base + 24576 + ls);
  };

  stageA_u(0, 0, 0); stageA_u(0, 0, 1);
  stageB_u(0, 0, 0); stageB_u(0, 0, 1);

  for (int ks = 0; ks < nsteps; ++ks) {
    const u16* base = sm + (ks & 1) * 32768;
    const int nb = (ks + 1) & 1;
    const bool more = (ks + 1 < nsteps);
    bf16x8 Ah[4], Al[4];

#pragma unroll
    for (int ph = 0; ph < 4; ++ph) {
      if (ph == 0) {
        asm volatile("s_waitcnt vmcnt(2)\n\ts_barrier" ::: "memory");
      } else if (ph == 2) {
        if (more) asm volatile("s_waitcnt vmcnt(4)\n\ts_barrier" ::: "memory");
        else      asm volatile("s_waitcnt vmcnt(0)\n\ts_barrier" ::: "memory");
      } else {
        __builtin_amdgcn_s_barrier();
      }
      if (ph == 0) {
#pragma unroll
        for (int i = 0; i < 4; ++i) {
          int ao = (q4 * 256 + wr * 64 + i * 16 + r16) * 8;
          Ah[i] = *(const bf16x8*)(base + ao);
          Al[i] = *(const bf16x8*)(base + 8192 + ao);
        }
      }
      const int j0 = ph * 2;
      int bo0 = (q4 * 256 + wc * 128 + j0 * 16 + r16) * 8;
      int bo1 = (q4 * 256 + wc * 128 + (j0 + 1) * 16 + r16) * 8;
      bf16x8 Bh0 = *(const bf16x8*)(base + 16384 + bo0);
      bf16x8 Bl0 = *(const bf16x8*)(base + 24576 + bo0);
      bf16x8 Bh1 = *(const bf16x8*)(base + 16384 + bo1);
      bf16x8 Bl1 = *(const bf16x8*)(base + 24576 + bo1);
      if (more) {
        if (ph == 0)      stageA_u(nb, ks + 1, 0);
        else if (ph == 1) stageA_u(nb, ks + 1, 1);
        else if (ph == 2) stageB_u(nb, ks + 1, 0);
        else              stageB_u(nb, ks + 1, 1);
      }
      asm volatile("s_waitcnt lgkmcnt(0)" ::: "memory");
      __builtin_amdgcn_sched_barrier(0);
      __builtin_amdgcn_s_setprio(1);
#pragma unroll
      for (int i = 0; i < 4; ++i)
        accv[i][j0] = __builtin_amdgcn_mfma_f32_16x16x32_bf16(Ah[i], Bh0, accv[i][j0], 0, 0, 0);
#pragma unroll
      for (int i = 0; i < 4; ++i)
        accv[i][j0] = __builtin_amdgcn_mfma_f32_16x16x32_bf16(Al[i], Bh0, accv[i][j0], 0, 0, 0);
#pragma unroll
      for (int i = 0; i < 4; ++i)
        accv[i][j0] = __builtin_amdgcn_mfma_f32_16x16x32_bf16(Ah[i], Bl0, accv[i][j0], 0, 0, 0);
#pragma unroll
      for (int i = 0; i < 4; ++i)
        accv[i][j0 + 1] = __builtin_amdgcn_mfma_f32_16x16x32_bf16(Ah[i], Bh1, accv[i][j0 + 1], 0, 0, 0);
#pragma unroll
      for (int i = 0; i < 4; ++i)
        accv[i][j0 + 1] = __builtin_amdgcn_mfma_f32_16x16x32_bf16(Al[i], Bh1, accv[i][j0 + 1], 0, 0, 0);
#pragma unroll
      for (int i = 0; i < 4; ++i)
        accv[i][j0 + 1] = __builtin_amdgcn_mfma_f32_16x16x32_bf16(Ah[i], Bl1, accv[i][j0 + 1], 0, 0, 0);
      __builtin_amdgcn_s_setprio(0);
    }
  }

  // ---- epilogue A: d^2 into accv; s/q reduce (FP chain order unchanged) ----
  double s = 0.0, qd = 0.0;
#pragma unroll
  for (int i = 0; i < 4; ++i) {
    const int mb = m0 + wr * 64 + i * 16 + q4 * 4;
    float xnv[4];
#pragma unroll
    for (int r = 0; r < 4; ++r) xnv[r] = xn[mb + r];
    float sf = 0.f, qf = 0.f;
#pragma unroll
    for (int j = 0; j < 8; ++j) {
      const int o = o0 + wc * 128 + j * 16 + r16;
      const float wnv = wn[o];              // zero-padded to Opad
#pragma unroll
      for (int r = 0; r < 4; ++r) {
        float d2 = xnv[r] + wnv - 2.f * accv[i][j][r];
        accv[i][j][r] = fmaxf(d2, 0.f) + 1e-12f;
      }
      if (o < O) {
#pragma unroll
        for (int r = 0; r < 4; ++r) { sf += fsqrt(accv[i][j][r]); qf += accv[i][j][r]; }
      }
    }
    s += sf; qd += qf;
  }
  for (int off = 32; off; off >>= 1) {
    s += __shfl_down(s, off, 64);
    qd += __shfl_down(qd, off, 64);
  }
  __syncthreads();                 // all waves past K-loop LDS reads
  double* redsm = (double*)sm;
  if (lane == 0) { redsm[w * 2] = s; redsm[w * 2 + 1] = qd; }
  __syncthreads();
  if (t == 0) {
    s = 0.0; qd = 0.0;
#pragma unroll
    for (int ww = 0; ww < 8; ++ww) { s += redsm[ww * 2]; qd += redsm[ww * 2 + 1]; }
    int stripe = (blockIdx.x + blockIdx.y * gridDim.x) & (STRIPES - 1);
    atomicAdd(&acc[accbase + stripe * 2], s);
    atomicAdd(&acc[accbase + stripe * 2 + 1], qd);
  }

  // ---- epilogue B: LDS transpose -> coalesced float4 stores ----
  float* smf = (float*)sm;         // [128][256] floats = 128 KB per half
#pragma unroll
  for (int h = 0; h < 2; ++h) {
    __syncthreads();               // (h=0: also fences t0's redsm reads)
    if ((wr >> 1) == h) {
      const int rbase = (wr & 1) * 64;
#pragma unroll
      for (int i = 0; i < 4; ++i) {
        const int row = rbase + i * 16 + q4 * 4;
#pragma unroll
        for (int j = 0; j < 8; ++j) {
          const int col = wc * 128 + j * 16 + r16;
#pragma unroll
          for (int r = 0; r < 4; ++r)
            smf[(row + r) * 256 + col] = accv[i][j][r];
        }
      }
    }
    __syncthreads();
    const int mbase = m0 + h * 128;
    const int oc = o0 + lane * 4;
    const bool ok = (oc + 4 <= Od);
#pragma unroll
    for (int rr = 0; rr < 16; ++rr) {
      const int row = w * 16 + rr;
      if (ok) {
        f32x4 v4 = *(const f32x4*)(smf + row * 256 + lane * 4);
        *(f32x4*)(dist + (size_t)(mbase + row) * Od + oc) = v4;
      }
    }
  }
}

__device__ __forceinline__ float block_inv_from_acc(
    const double* __restrict__ acc, int base, double n, float* sh)
{
  __syncthreads();
  int t = threadIdx.x;
  if (t < 64) {
    double s = acc[base + 2 * t], q = acc[base + 2 * t + 1];
    for (int off = 32; off; off >>= 1) {
      s += __shfl_down(s, off, 64);
      q += __shfl_down(q, off, 64);
    }
    if (t == 0) {
      double var = (q - s * s / n) / (n - 1.0);
      *sh = var > 0.0 ? (float)(0.5 / var) : __builtin_inff();
    }
  }
  __syncthreads();
  return *sh;
}

// exp -> crelu(cb1) -> [0.81,0.9,1]/3 pool -> hi/lo (Kp=256) + xn   (dist2 = d^2, ldd)
__global__ __launch_bounds__(256) void l2_sfm(
    const float* __restrict__ dist2, const double* __restrict__ acc, double n,
    const float* __restrict__ cb, u16* __restrict__ Xhi, u16* __restrict__ Xlo,
    float* __restrict__ xn, int c0, int ldd, int sdistc, int sXc, int sxnc)
{
  __shared__ float shinv;
  __shared__ float red[4];
  int zi = blockIdx.z, c = c0 + zi;
  dist2 += (size_t)zi * sdistc;
  Xhi += (size_t)zi * sXc; Xlo += (size_t)zi * sXc; xn += (size_t)zi * sxnc;
  float inv = block_inv_from_acc(acc + (size_t)c * ACC_TOTAL, ACC_L2, n, &shinv);
  int b = blockIdx.x, u = blockIdx.y, ch = threadIdx.x;
  float bias = cb[1];
  float v = 0.f;
  if (ch < 225) {
    const float av[3] = {0.81f, 0.9f, 1.0f};
    float a = 0.f;
#pragma unroll
    for (int vv = 0; vv < 3; ++vv) {
      float d2 = dist2[((size_t)b * 9 + u * 3 + vv) * ldd + ch];
      float e = fexp(-d2 * inv);
      e = (e >= bias) ? e : 0.f;
      a = fmaf(e, av[vv], a);
    }
    v = a * (1.f / 3.f);
  }
  size_t row = (size_t)b * 3 + u;
  u16 h = f2bf(v);
  u16 l = f2bf(v - bf2f(h));
  Xhi[row * 256 + ch] = h;
  Xlo[row * 256 + ch] = l;
  float p = v * v;
  for (int off = 32; off; off >>= 1) p += __shfl_down(p, off, 64);
  if ((ch & 63) == 0) red[ch >> 6] = p;
  __syncthreads();
  if (ch == 0) xn[row] = red[0] + red[1] + red[2] + red[3];
}

// exp -> crelu(cb2) -> [0.81,0.9,1]/3 pool -> hi/lo (Kp=640) + xn   (dist3 = d^2, ldd)
__global__ __launch_bounds__(256) void l3_sfm(
    const float* __restrict__ dist3, const double* __restrict__ acc, double n,
    const float* __restrict__ cb, u16* __restrict__ Xhi, u16* __restrict__ Xlo,
    float* __restrict__ xn, int c0, int ldd, int sdistc, int sXc, int sxnc)
{
  __shared__ float shinv;
  __shared__ float red[4];
  int zi = blockIdx.y, c = c0 + zi;
  dist3 += (size_t)zi * sdistc;
  Xhi += (size_t)zi * sXc; Xlo += (size_t)zi * sXc; xn += (size_t)zi * sxnc;
  float inv = block_inv_from_acc(acc + (size_t)c * ACC_TOTAL, ACC_L3, n, &shinv);
  int b = blockIdx.x, t = threadIdx.x;
  float bias = cb[2];
  const float au[3] = {0.81f, 0.9f, 1.0f};
  float p = 0.f;
  for (int ch = t; ch < 640; ch += 256) {
    float v = 0.f;
    if (ch < 625) {
      float a = 0.f;
#pragma unroll
      for (int u = 0; u < 3; ++u) {
        float d2 = dist3[((size_t)b * 3 + u) * ldd + ch];
        float e = fexp(-d2 * inv);
        e = (e >= bias) ? e : 0.f;
        a = fmaf(e, au[u], a);
      }
      v = a * (1.f / 3.f);
    }
    u16 h = f2bf(v);
    u16 l = f2bf(v - bf2f(h));
    Xhi[(size_t)b * 640 + ch] = h;
    Xlo[(size_t)b * 640 + ch] = l;
    p = fmaf(v, v, p);
  }
  for (int off = 32; off; off >>= 1) p += __shfl_down(p, off, 64);
  if ((t & 63) == 0) red[t >> 6] = p;
  __syncthreads();
  if (t == 0) xn[b] = red[0] + red[1] + red[2] + red[3];
}

// L4 exp/crelu fused into FC; loops nc channels internally  (dist4 = d^2, ldd)
__global__ __launch_bounds__(128) void fc_acc(
    const float* __restrict__ dist4, const double* __restrict__ acc, double n,
    const float* __restrict__ cb, const float* __restrict__ fcw,
    const float* __restrict__ fcb, float* __restrict__ out,
    int c0, int nc, int ldd, int sdistc)
{
  __shared__ float shinv;
  int b = blockIdx.x, t = threadIdx.x;
  float bias = cb[3];
  float p[10];
#pragma unroll
  for (int k = 0; k < 10; ++k) p[k] = 0.f;
  for (int zi = 0; zi < nc; ++zi) {
    int c = c0 + zi;
    float inv = block_inv_from_acc(acc + (size_t)c * ACC_TOTAL, ACC_L4, n, &shinv);
    const float* d4 = dist4 + (size_t)zi * sdistc;
    for (int j = t; j < 1225; j += 128) {
      float d2 = d4[(size_t)b * ldd + j];
      float v = fexp(-d2 * inv);
      v = (v >= bias) ? v : 0.f;
#pragma unroll
      for (int k = 0; k < 10; ++k) p[k] = fmaf(v, fcw[k * 3675 + c * 1225 + j], p[k]);
    }
  }
#pragma unroll
  for (int k = 0; k < 10; ++k)
    for (int off = 32; off; off >>= 1) p[k] += __shfl_down(p[k], off, 64);
  __shared__ float red[2][10];
  int wave = t >> 6;
  if ((t & 63) == 0) {
#pragma unroll
    for (int k = 0; k < 10; ++k) red[wave][k] = p[k];
  }
  __syncthreads();
  if (t < 10) {
    float v = red[0][t] + red[1][t];
    if (c0 == 0) out[(size_t)b * 10 + t] = fcb[t] + v;
    else         out[(size_t)b * 10 + t] += v;
  }
}

extern "C" void kernel_launch(void* const* d_in, const int* in_sizes, int n_in,
                              void* d_out, int out_size, void* d_ws, size_t ws_size,
                              hipStream_t stream) {
  const float* x   = (const float*)d_in[0];
  const float* w1  = (const float*)d_in[1];
  const float* w2  = (const float*)d_in[2];
  const float* w3  = (const float*)d_in[3];
  const float* w4  = (const float*)d_in[4];
  const float* fcw = (const float*)d_in[5];
  const float* fcb = (const float*)d_in[6];
  const float* cb  = (const float*)d_in[7];
  float* out = (float*)d_out;
  const int B = in_sizes[0] / (3 * 28 * 28);   // 4096
  const int M2 = B * 9, M3 = B * 3;
  const int NB = B / 2;
  const int LD2 = 240, LD3 = 640, LD4 = 1232;  // 16B-aligned dist leading dims

  const size_t W2SZ = 256 * 128, W3SZ = 768 * 256, W4SZ = (size_t)1280 * 640;
  const size_t WTOT = 3 * (W2SZ + W3SZ + W4SZ);

  // tier 0: L1 batched (d1 x3) + L2-4 batched; tier 1: L1 serial, L2-4 batched;
  // tier 2: everything channel-serial.
  int tier;
  u16 *Xbase, *Whi, *Wlo, *W1h, *W1l;
  float *wn, *w1n, *xn, *inv36, *part;
  double* accd;
  float* Sf;
  for (tier = 0; tier < 3; ++tier) {
    size_t cur = 0;
    char* basep = (char*)d_ws;
    auto take = [&](size_t bytes) {
      void* r = basep + cur;
      cur = (cur + bytes + 255) & ~(size_t)255;
      return r;
    };
    int nc = (tier <= 1) ? 3 : 1;
    int ncL1 = (tier == 0) ? 3 : 1;
    size_t Ssz = (size_t)M2 * LD2 * 4 * nc;
    size_t d1sz = (size_t)B * 3600 * 4 * ncL1;
    if (d1sz > Ssz) Ssz = d1sz;
    size_t d3sz = (size_t)M3 * LD3 * 4 * nc;
    if (d3sz > Ssz) Ssz = d3sz;
    size_t d4sz = (size_t)B * LD4 * 4 * nc;
    if (d4sz > Ssz) Ssz = d4sz;
    Sf = (float*)take(Ssz);
    Xbase = (u16*)take((size_t)M2 * 128 * 2 * 2 * nc);
    Whi = (u16*)take(WTOT * 2); Wlo = (u16*)take(WTOT * 2);
    W1h = (u16*)take(12288 * 2); W1l = (u16*)take(12288 * 2);
    wn  = (float*)take(3 * (256 + 768 + 1280) * 4);
    w1n = (float*)take(384 * 4);
    xn    = (float*)take((size_t)M2 * 4 * nc);
    inv36 = (float*)take(40 * 4 * ncL1);
    part  = (float*)take((size_t)72 * NB * 4 * ncL1);
    accd  = (double*)take(3 * ACC_TOTAL * 8);
    if (cur <= ws_size || tier == 2) break;
  }
  const int nc = (tier <= 1) ? 3 : 1;
  const bool batL1 = (tier == 0);

  const int sX2c   = (nc == 3) ? M2 * 128 * 2 : 0;
  const int sX3c   = (nc == 3) ? M3 * 256 * 2 : 0;
  const int sX4c   = (nc == 3) ? B * 640 * 2 : 0;
  const int sD2c   = (nc == 3) ? M2 * LD2 : 0;
  const int sD3c   = (nc == 3) ? M3 * LD3 : 0;
  const int sD4c   = (nc == 3) ? B * LD4 : 0;
  const int sXn2c  = (nc == 3) ? M2 : 0;
  const int sXn3c  = (nc == 3) ? M3 : 0;
  const int sXn4c  = (nc == 3) ? B : 0;
  const int sD1c   = batL1 ? B * 3600 : 0;
  const int sPartc = batL1 ? 72 * NB : 0;
  const int sInvL1 = batL1 ? 40 : 0;

  u16* x2hi = Xbase;   u16* x2lo = Xbase + (size_t)M2 * 128;
  u16* x3hi = Xbase;   u16* x3lo = Xbase + (size_t)M3 * 256;
  u16* x4hi = Xbase;   u16* x4lo = Xbase + (size_t)B * 640;
  u16* Whi2 = Whi;                 u16* Wlo2 = Wlo;                 float* wn2 = wn;
  u16* Whi3 = Whi + 3 * W2SZ;      u16* Wlo3 = Wlo + 3 * W2SZ;      float* wn3 = wn + 3 * 256;
  u16* Whi4 = Whi + 3 * (W2SZ + W3SZ); u16* Wlo4 = Wlo + 3 * (W2SZ + W3SZ);
  float* wn4 = wn + 3 * (256 + 768);

  // one prep dispatch: 9 zero-blocks + 384 + 768 + 2304 + 3840 w_prep blocks
  prep_all<<<9 + 384 + 768 + 2304 + 3840, 128, 0, stream>>>(
      w1, w2, w3, w4, W1h, W1l, Whi2, Wlo2, Whi3, Wlo3, Whi4, Wlo4,
      w1n, wn2, wn3, wn4, accd, 3 * ACC_TOTAL);

  for (int c0 = 0; c0 < 3; c0 += nc) {
    // ---- L1 ----
    if (batL1) {
      l1_gemm_d2<<<dim3(NB, 3), 256, 0, stream>>>(x, 0, W1h, W1l, w1n, Sf, sD1c,
                                                  part, sPartc, NB);
      l1_part_fin<<<dim3(36, 3), 256, 0, stream>>>(part, sPartc, inv36, sInvL1,
                                                   (double)B * 100.0, NB);
      l1_sfm_lite<<<dim3(B, 3), 128, 0, stream>>>(
          Sf, sD1c, inv36, sInvL1, cb, x2hi, x2lo, xn, sX2c, sXn2c);
    } else {
      for (int ci = 0; ci < nc; ++ci) {
        int c = c0 + ci;
        l1_gemm_d2<<<dim3(NB, 1), 256, 0, stream>>>(x, c, W1h, W1l, w1n, Sf, 0,
                                                    part, 0, NB);
        l1_part_fin<<<dim3(36, 1), 256, 0, stream>>>(part, 0, inv36, 0,
                                                     (double)B * 100.0, NB);
        l1_sfm_lite<<<dim3(B, 1), 128, 0, stream>>>(
            Sf, 0, inv36, 0, cb, x2hi + (size_t)ci * sX2c, x2lo + (size_t)ci * sX2c,
            xn + (size_t)ci * sXn2c, 0, 0);
      }
    }

    // L2: (M2 x 128) x (256 x 128) -> dist2 (M2 x 225, ld 240)
    gemm_dist_pipe<<<dim3(M2 / 256, 1, nc), 512, 0, stream>>>(
        x2hi, x2lo, Whi2, Wlo2, xn, wn2, Sf, 225, LD2, 128, accd, ACC_L2, c0,
        sX2c, (int)W2SZ, sXn2c, 256, sD2c);
    l2_sfm<<<dim3(B, 3, nc), 256, 0, stream>>>(
        Sf, accd, (double)M2 * 225.0, cb, x3hi, x3lo, xn, c0, LD2, sD2c, sX3c, sXn3c);

    // L3: (M3 x 256) x (768 x 256) -> dist3 (M3 x 625, ld 640)
    gemm_dist_pipe<<<dim3(M3 / 256, 3, nc), 512, 0, stream>>>(
        x3hi, x3lo, Whi3, Wlo3, xn, wn3, Sf, 625, LD3, 256, accd, ACC_L3, c0,
        sX3c, (int)W3SZ, sXn3c, 768, sD3c);
    l3_sfm<<<dim3(B, nc), 256, 0, stream>>>(
        Sf, accd, (double)M3 * 625.0, cb, x4hi, x4lo, xn, c0, LD3, sD3c, sX4c, sXn4c);

    // L4: (B x 640) x (1280 x 640) -> dist4 (B x 1225, ld 1232)
    gemm_dist_pipe<<<dim3(B / 256, 5, nc), 512, 0, stream>>>(
        x4hi, x4lo, Whi4, Wlo4, xn, wn4, Sf, 1225, LD4, 640, accd, ACC_L4, c0,
        sX4c, (int)W4SZ, sXn4c, 1280, sD4c);
    fc_acc<<<B, 128, 0, stream>>>(
        Sf, accd, (double)B * 1225.0, cb, fcw, fcb, out, c0, nc, LD4, sD4c);
  }
}

// Round 10
// 529.898 us; speedup vs baseline: 1.0291x; 1.0291x over previous
//
#include <hip/hip_runtime.h>

// SOMNetwork forward. All four rbf/cdist layers via split-bf16 MFMA GEMM
// (hi/lo decomposition, 3 MFMAs/product).
// Round 18 (resubmit; r9 bench was an infra failure, kernel re-audited):
// r8 LDS-transpose C-store REVERTED (bank conflicts 0->885K, WRITE up,
// +4 barriers -> 72->94us). Back to r5 scattered stores (bitwise-proven).
// NEW: GEMM tile 256x256 -> 128x128 (8 waves, wave-tile 32x64, acc[2][4]).
// LDS 2x32KB=64KB -> 2 blocks/CU (4 waves/SIMD); grids 1728/1728/960 blocks
// (was 432/108/240 at 1 block/CU -- L3 used 42% of CUs). Cross-block overlap
// replaces intra-block pipelining (m114). Counted-vmcnt stage-before-wait
// loop: stage(ks+1) -> vmcnt(4) -> barrier -> ds_read+MFMA -> barrier.
// L1: d1 materialization; l1_gemm_d2 (LDS-transpose s/q reduce + cvt_pk
// hi/lo split) + l1_sfm_lite BW-bound re-read. prep_all merges zero+w_prep.
// Channels batched into grid z. Tiered ws fallback keeps old plans valid.

typedef unsigned short u16;
typedef short bf16x8 __attribute__((ext_vector_type(8)));
typedef float f32x4 __attribute__((ext_vector_type(4)));
typedef unsigned int u32;
typedef u32 u32x4 __attribute__((ext_vector_type(4)));

#define STRIPES 64
#define ACC_L2 0            // 64 stripes * 2 doubles per layer region
#define ACC_L3 128
#define ACC_L4 256
#define ACC_TOTAL 384

__device__ __forceinline__ u16 f2bf(float f) {
  unsigned int u = __float_as_uint(f);
  unsigned int r = (u + 0x7fffu + ((u >> 16) & 1u)) >> 16;
  return (u16)r;
}
__device__ __forceinline__ float bf2f(u16 h) {
  return __uint_as_float(((unsigned int)h) << 16);
}
// packed RNE bf16 convert: low16 = bf16(a), high16 = bf16(b)
__device__ __forceinline__ u32 cvtpk_bf16(float a, float b) {
  u32 r;
  asm("v_cvt_pk_bf16_f32 %0, %1, %2" : "=v"(r) : "v"(a), "v"(b));
  return r;
}
__device__ __forceinline__ float fexp(float x) { return __expf(x); }
__device__ __forceinline__ float fsqrt(float x) { return __builtin_amdgcn_sqrtf(x); }
__device__ __forceinline__ void gload16(const void* g, const void* l) {
  __builtin_amdgcn_global_load_lds(
      (const __attribute__((address_space(1))) unsigned int*)g,
      (__attribute__((address_space(3))) unsigned int*)l, 16, 0, 0);
}

// ---------------- prep_all: zero acc + all four w_preps in one dispatch ----------------
// block map: [0,9) zero acc; then L1 384, L2 768, L3 2304, L4 3840 blocks.
__global__ __launch_bounds__(128) void prep_all(
    const float* __restrict__ w1, const float* __restrict__ w2,
    const float* __restrict__ w3, const float* __restrict__ w4,
    u16* __restrict__ W1h, u16* __restrict__ W1l,
    u16* __restrict__ Whi2, u16* __restrict__ Wlo2,
    u16* __restrict__ Whi3, u16* __restrict__ Wlo3,
    u16* __restrict__ Whi4, u16* __restrict__ Wlo4,
    float* __restrict__ w1n, float* __restrict__ wn2,
    float* __restrict__ wn3, float* __restrict__ wn4,
    double* __restrict__ accd, int naccd)
{
  __shared__ float red[2];
  int bid = blockIdx.x, t = threadIdx.x;
  if (bid < 9) {
    int i = bid * 128 + t;
    if (i < naccd) accd[i] = 0.0;
    return;
  }
  bid -= 9;
  const float* W; u16 *hi, *lo; float* wn; int O, K, Opad, Kp;
  if (bid < 384)        { W = w1; hi = W1h;  lo = W1l;  wn = w1n; O = 100;  K = 25;  Opad = 128;  Kp = 32;  }
  else if (bid < 1152)  { bid -= 384;  W = w2; hi = Whi2; lo = Wlo2; wn = wn2; O = 225;  K = 100; Opad = 256;  Kp = 128; }
  else if (bid < 3456)  { bid -= 1152; W = w3; hi = Whi3; lo = Wlo3; wn = wn3; O = 625;  K = 225; Opad = 768;  Kp = 256; }
  else                  { bid -= 3456; W = w4; hi = Whi4; lo = Wlo4; wn = wn4; O = 1225; K = 625; Opad = 1280; Kp = 640; }
  int o = bid % Opad, cc = bid / Opad;
  const float* src = W + ((size_t)cc * O + o) * K;
  u16* dh = hi + ((size_t)cc * Opad + o) * Kp;
  u16* dl = lo + ((size_t)cc * Opad + o) * Kp;
  float p = 0.f;
  for (int k = t; k < Kp; k += 128) {
    float v = (o < O && k < K) ? src[k] : 0.f;
    u16 h = f2bf(v);
    u16 l = f2bf(v - bf2f(h));
    dh[k] = h; dl[k] = l;
    p = fmaf(v, v, p);
  }
  for (int off = 32; off; off >>= 1) p += __shfl_down(p, off, 64);
  if ((t & 63) == 0) red[t >> 6] = p;
  __syncthreads();
  if (t == 0) wn[(size_t)cc * Opad + o] = red[0] + red[1];
}

// ---------------- L1 GEMM pass: fused patch extraction + MFMA + d^2 store ----------------
__global__ __launch_bounds__(256) void l1_gemm_d2(
    const float* __restrict__ x, int c0,
    const u16* __restrict__ W1h, const u16* __restrict__ W1l,
    const float* __restrict__ w1n, float* __restrict__ dist1, int sD1c,
    float* __restrict__ part, int sPartc, int NBLK)
{
  __shared__ __align__(16) u16 sm[16384];   // patches+W (32 KB) -> reused as smf[2][36][66]
  __shared__ float img[1568];
  __shared__ float pnsm[512];
  __shared__ float pnloc[128];
  const int t = threadIdx.x;
  const int w = t >> 6, lane = t & 63;
  const int b0 = blockIdx.x * 2;
  const int zi = blockIdx.y, c = c0 + zi;
  const u16* Wh = W1h + (size_t)c * 4096;
  const u16* Wl = W1l + (size_t)c * 4096;
  const float* wn = w1n + (size_t)c * 128;
  dist1 += (size_t)zi * sD1c;
  part  += (size_t)zi * sPartc;

  {
    const int kk = (w & 3) * 8;
#pragma unroll
    for (int u = 0; u < 2; ++u) {
      const size_t gb = (size_t)(u * 64 + lane) * 32 + kk;
      const int ls = ((w & 3) * 128 + u * 64) * 8;
      gload16(Wh + gb, sm + 8192 + ls);
      gload16(Wl + gb, sm + 12288 + ls);
    }
  }
#pragma unroll
  for (int im = 0; im < 2; ++im) {
    if (t < 196)
      ((float4*)(img + im * 784))[t] =
          ((const float4*)(x + ((size_t)(b0 + im) * 3 + c) * 784))[t];
  }
  __syncthreads();
  for (int s = t; s < 512; s += 256) {
    int q = s >> 7, row = s & 127;
    int im = row >> 6, pr = row & 63;
    int pi = pr / 6, pj = pr - pi * 6;
    const float* ib = img + im * 784 + pi * 4 * 28 + pj * 4;
    float v[8]; float pn = 0.f;
#pragma unroll
    for (int e = 0; e < 8; ++e) {
      int k = q * 8 + e;
      float val = 0.f;
      if (pr < 36 && k < 25) { int r = k / 5, ss = k - r * 5; val = ib[r * 28 + ss]; }
      v[e] = val; pn = fmaf(val, val, pn);
    }
    u32x4 hp, lp;
#pragma unroll
    for (int e = 0; e < 4; ++e) {
      u32 h = cvtpk_bf16(v[2 * e], v[2 * e + 1]);
      float l0 = v[2 * e]     - __uint_as_float(h << 16);
      float l1 = v[2 * e + 1] - __uint_as_float(h & 0xffff0000u);
      hp[e] = h;
      lp[e] = cvtpk_bf16(l0, l1);
    }
    *(u32x4*)(sm + (q * 128 + row) * 8) = hp;
    *(u32x4*)(sm + 4096 + (q * 128 + row) * 8) = lp;
    pnsm[s] = pn;
  }
  asm volatile("s_waitcnt vmcnt(0)" ::: "memory");
  __syncthreads();
  if (t < 128) pnloc[t] = pnsm[t] + pnsm[128 + t] + pnsm[256 + t] + pnsm[384 + t];

  const int wr = w >> 1, wc = w & 1;
  const int q4 = lane >> 4, r16 = lane & 15;
  f32x4 accv[4][4];
#pragma unroll
  for (int i = 0; i < 4; ++i)
#pragma unroll
    for (int j = 0; j < 4; ++j) accv[i][j] = (f32x4){0.f, 0.f, 0.f, 0.f};

  bf16x8 Ah[4], Al[4], Bh[4], Bl[4];
#pragma unroll
  for (int i = 0; i < 4; ++i) {
    int ao = (q4 * 128 + wr * 64 + i * 16 + r16) * 8;
    int bo = (q4 * 128 + wc * 64 + i * 16 + r16) * 8;
    Ah[i] = *(const bf16x8*)(sm + ao);
    Al[i] = *(const bf16x8*)(sm + 4096 + ao);
    Bh[i] = *(const bf16x8*)(sm + 8192 + bo);
    Bl[i] = *(const bf16x8*)(sm + 12288 + bo);
  }
#pragma unroll
  for (int j = 0; j < 4; ++j) {
#pragma unroll
    for (int i = 0; i < 4; ++i)
      accv[i][j] = __builtin_amdgcn_mfma_f32_16x16x32_bf16(Ah[i], Bh[j], accv[i][j], 0, 0, 0);
#pragma unroll
    for (int i = 0; i < 4; ++i)
      accv[i][j] = __builtin_amdgcn_mfma_f32_16x16x32_bf16(Al[i], Bh[j], accv[i][j], 0, 0, 0);
#pragma unroll
    for (int i = 0; i < 4; ++i)
      accv[i][j] = __builtin_amdgcn_mfma_f32_16x16x32_bf16(Ah[i], Bl[j], accv[i][j], 0, 0, 0);
  }
  __syncthreads();   // all fragment reads of sm done -> safe to reuse as smf

  // s/q partials via LDS transpose: smf[kind][pos][w*16+r16], stride 66.
  float* smf = (float*)sm;
  int colv[4]; float wnv[4];
#pragma unroll
  for (int j = 0; j < 4; ++j) {
    colv[j] = wc * 64 + j * 16 + r16;
    wnv[j] = (colv[j] < 100) ? wn[colv[j]] : 0.f;
  }
#pragma unroll
  for (int i = 0; i < 4; ++i) {
#pragma unroll
    for (int r = 0; r < 4; ++r) {
      int pos = i * 16 + q4 * 4 + r;
      if (pos < 36) {           // uniform within each 16-lane (r16) group
        float pn = pnloc[wr * 64 + pos];
        float* drow = dist1 + ((size_t)(b0 + wr) * 36 + pos) * 100;
        float sl = 0.f, ql = 0.f;
#pragma unroll
        for (int j = 0; j < 4; ++j) {
          if (colv[j] < 100) {
            float d2 = pn + wnv[j] - 2.f * accv[i][j][r];
            float d2c = fmaxf(d2, 0.f) + 1e-12f;
            drow[colv[j]] = d2c;
            sl += fsqrt(d2c); ql += d2c;
          }
        }
        smf[pos * 66 + w * 16 + r16] = sl;
        smf[(36 + pos) * 66 + w * 16 + r16] = ql;
      }
    }
  }
  __syncthreads();
  if (t < 72) {
    const float* row = smf + (size_t)t * 66;
    float v0 = 0.f;
#pragma unroll
    for (int k = 0; k < 64; ++k) v0 += row[k];
    part[(size_t)t * NBLK + blockIdx.x] = v0;
  }
}

// ---------------- L1 partial finish: per-block partials -> inv36 ----------------
__global__ __launch_bounds__(256) void l1_part_fin(
    const float* __restrict__ part, int sPartc, float* __restrict__ inv36, int sInvc,
    double n, int NBLK)
{
  __shared__ double sh[8];
  int pos = blockIdx.x, zi = blockIdx.y, t = threadIdx.x;
  part += (size_t)zi * sPartc; inv36 += (size_t)zi * sInvc;
  double s = 0.0, q = 0.0;
  for (int b = t; b < NBLK; b += 256) {
    s += part[(size_t)pos * NBLK + b];
    q += part[(size_t)(36 + pos) * NBLK + b];
  }
  for (int off = 32; off; off >>= 1) {
    s += __shfl_down(s, off, 64);
    q += __shfl_down(q, off, 64);
  }
  if ((t & 63) == 0) { sh[(t >> 6) * 2] = s; sh[(t >> 6) * 2 + 1] = q; }
  __syncthreads();
  if (t == 0) {
    s = sh[0] + sh[2] + sh[4] + sh[6];
    q = sh[1] + sh[3] + sh[5] + sh[7];
    double var = (q - s * s / n) / (n - 1.0);
    inv36[pos] = var > 0.0 ? (float)(0.5 / var) : __builtin_inff();
  }
}

// ---------------- L1 sfm: d^2 -> exp/crelu -> 2x2 alpha-pool -> X hi/lo + xn ----------------
__global__ __launch_bounds__(128) void l1_sfm_lite(
    const float* __restrict__ d1, int sD1c,
    const float* __restrict__ inv36, int sInvc, const float* __restrict__ cb,
    u16* __restrict__ Xhi, u16* __restrict__ Xlo, float* __restrict__ xn,
    int sXc, int sxnc)
{
  __shared__ float inv_s[36];
  __shared__ float xnsm[9][2];
  int b = blockIdx.x, zi = blockIdx.y, t = threadIdx.x;
  d1 += (size_t)zi * sD1c; inv36 += (size_t)zi * sInvc;
  Xhi += (size_t)zi * sXc; Xlo += (size_t)zi * sXc; xn += (size_t)zi * sxnc;
  if (t < 36) inv_s[t] = inv36[t];
  __syncthreads();
  const float* db = d1 + (size_t)b * 3600;
  float bias = cb[0];
  int wv = t >> 6;
#pragma unroll
  for (int IJ = 0; IJ < 9; ++IJ) {
    const int I = IJ / 3, J = IJ - I * 3;
    const int p00 = 12 * I + 2 * J;
    float v = 0.f;
    if (t < 100) {
      float e00 = fexp(-db[p00 * 100 + t] * inv_s[p00]);
      float e01 = fexp(-db[(p00 + 1) * 100 + t] * inv_s[p00 + 1]);
      float e10 = fexp(-db[(p00 + 6) * 100 + t] * inv_s[p00 + 6]);
      float e11 = fexp(-db[(p00 + 7) * 100 + t] * inv_s[p00 + 7]);
      e00 = (e00 >= bias) ? e00 : 0.f;
      e01 = (e01 >= bias) ? e01 : 0.f;
      e10 = (e10 >= bias) ? e10 : 0.f;
      e11 = (e11 >= bias) ? e11 : 0.f;
      v = 0.25f * (fmaf(0.729f, e00, 0.81f * e01) + fmaf(0.9f, e10, e11));
    }
    size_t xrow = (size_t)b * 9 + IJ;
    u16 h = f2bf(v);
    u16 l = f2bf(v - bf2f(h));
    Xhi[xrow * 128 + t] = h;
    Xlo[xrow * 128 + t] = l;
    float p = v * v;
    for (int off = 32; off; off >>= 1) p += __shfl_down(p, off, 64);
    if ((t & 63) == 0) xnsm[IJ][wv] = p;
  }
  __syncthreads();
  if (t < 9) xn[(size_t)b * 9 + t] = xnsm[t][0] + xnsm[t][1];
}

// ---------------- 128x128-tile 8-wave counted-vmcnt split-bf16 MFMA cdist GEMM ----------------
// 2 blocks/CU (64 KB LDS), 4 waves/SIMD: cross-block overlap hides the
// stage/barrier stalls (m114). Per K-step: stage(ks+1) [4 loads] ->
// vmcnt(4) [tile ks landed, ks+1 in flight] -> barrier -> ds_read + MFMA
// (FP order per accv[i][j]: hh, lh, hl; i ascending) -> barrier.
// Wave-tile 32x64: wr=w>>1 (row stripe), wc=w&1 (col half), acc[2][4].
__global__ __launch_bounds__(512, 4) void gemm_dist_pipe(
    const u16* __restrict__ Xhi, const u16* __restrict__ Xlo,
    const u16* __restrict__ Whi, const u16* __restrict__ Wlo,
    const float* __restrict__ xn, const float* __restrict__ wn,
    float* __restrict__ dist, int O, int Kp,
    double* __restrict__ acc, int accbase, int c0,
    int sXc, int sWc, int sxnc, int swnc, int sdistc)
{
  __shared__ __align__(16) u16 sm[32768];   // 64 KB: buffers at 0 and 16384
  int zi = blockIdx.z, c = c0 + zi;
  Xhi += (size_t)zi * sXc; Xlo += (size_t)zi * sXc;
  Whi += (size_t)c * sWc;  Wlo += (size_t)c * sWc;
  xn += (size_t)zi * sxnc; wn += (size_t)c * swnc;
  dist += (size_t)zi * sdistc;
  acc += (size_t)c * ACC_TOTAL;

  const int t = threadIdx.x;
  const int w = t >> 6, lane = t & 63;
  const int wr = w >> 1, wc = w & 1;
  const int sq = w & 3, half = w >> 2;
  const int m0 = blockIdx.x * 128, o0 = blockIdx.y * 128;
  const int q4 = lane >> 4, r16 = lane & 15;
  const int nsteps = Kp / 32;

  f32x4 accv[2][4];
#pragma unroll
  for (int i = 0; i < 2; ++i)
#pragma unroll
    for (int j = 0; j < 4; ++j) accv[i][j] = (f32x4){0.f, 0.f, 0.f, 0.f};

  // per K-step: 4 gload16/thread stage the full 32KB tile pair.
  // LDS layout per buffer (u16): Xhi [0,4K) Xlo [4K,8K) Whi [8K,12K) Wlo [12K,16K);
  // within each: (kquarter*128 + row)*8.
  auto stage = [&](int buf, int ks) {
    const int kk = ks * 32 + sq * 8;
    u16* base = sm + buf * 16384;
    const int row = half * 64 + lane;
    const size_t ga = (size_t)(m0 + row) * Kp + kk;
    const size_t gb = (size_t)(o0 + row) * Kp + kk;
    const int ls = (sq * 128 + row) * 8;
    gload16(Xhi + ga, base + ls);
    gload16(Xlo + ga, base + 4096 + ls);
    gload16(Whi + gb, base + 8192 + ls);
    gload16(Wlo + gb, base + 12288 + ls);
  };

  stage(0, 0);
  for (int ks = 0; ks < nsteps; ++ks) {
    const u16* base = sm + (ks & 1) * 16384;
    const bool more = (ks + 1 < nsteps);
    if (more) stage((ks + 1) & 1, ks + 1);
    if (more) asm volatile("s_waitcnt vmcnt(4)\n\ts_barrier" ::: "memory");
    else      asm volatile("s_waitcnt vmcnt(0)\n\ts_barrier" ::: "memory");

    bf16x8 Ah[2], Al[2];
#pragma unroll
    for (int i = 0; i < 2; ++i) {
      int ao = (q4 * 128 + wr * 32 + i * 16 + r16) * 8;
      Ah[i] = *(const bf16x8*)(base + ao);
      Al[i] = *(const bf16x8*)(base + 4096 + ao);
    }
    __builtin_amdgcn_s_setprio(1);
#pragma unroll
    for (int j = 0; j < 4; ++j) {
      int bo = (q4 * 128 + wc * 64 + j * 16 + r16) * 8;
      bf16x8 Bh = *(const bf16x8*)(base + 8192 + bo);
      bf16x8 Bl = *(const bf16x8*)(base + 12288 + bo);
#pragma unroll
      for (int i = 0; i < 2; ++i)
        accv[i][j] = __builtin_amdgcn_mfma_f32_16x16x32_bf16(Ah[i], Bh, accv[i][j], 0, 0, 0);
#pragma unroll
      for (int i = 0; i < 2; ++i)
        accv[i][j] = __builtin_amdgcn_mfma_f32_16x16x32_bf16(Al[i], Bh, accv[i][j], 0, 0, 0);
#pragma unroll
      for (int i = 0; i < 2; ++i)
        accv[i][j] = __builtin_amdgcn_mfma_f32_16x16x32_bf16(Ah[i], Bl, accv[i][j], 0, 0, 0);
    }
    __builtin_amdgcn_s_setprio(0);
    asm volatile("s_barrier" ::: "memory");
  }

  double s = 0.0, qd = 0.0;
#pragma unroll
  for (int i = 0; i < 2; ++i) {
    const int mb = m0 + wr * 32 + i * 16 + q4 * 4;
    float xnv[4];
#pragma unroll
    for (int r = 0; r < 4; ++r) xnv[r] = xn[mb + r];
    float sf = 0.f, qf = 0.f;
#pragma unroll
    for (int j = 0; j < 4; ++j) {
      const int o = o0 + wc * 64 + j * 16 + r16;
      if (o < O) {
        const float wnv = wn[o];
#pragma unroll
        for (int r = 0; r < 4; ++r) {
          float d2 = xnv[r] + wnv - 2.f * accv[i][j][r];
          float d2c = fmaxf(d2, 0.f) + 1e-12f;
          dist[(size_t)(mb + r) * O + o] = d2c;
          sf += fsqrt(d2c); qf += d2c;
        }
      }
    }
    s += sf; qd += qf;
  }
  for (int off = 32; off; off >>= 1) {
    s += __shfl_down(s, off, 64);
    qd += __shfl_down(qd, off, 64);
  }
  // use the LDS buffer NOT read by the final K-step (nsteps even -> buffer 0)
  double* redsm = (double*)(sm + (nsteps & 1) * 16384);
  if (lane == 0) { redsm[w * 2] = s; redsm[w * 2 + 1] = qd; }
  __syncthreads();
  if (t == 0) {
    s = 0.0; qd = 0.0;
#pragma unroll
    for (int ww = 0; ww < 8; ++ww) { s += redsm[ww * 2]; qd += redsm[ww * 2 + 1]; }
    int stripe = (blockIdx.x + blockIdx.y * gridDim.x) & (STRIPES - 1);
    atomicAdd(&acc[accbase + stripe * 2], s);
    atomicAdd(&acc[accbase + stripe * 2 + 1], qd);
  }
}

__device__ __forceinline__ float block_inv_from_acc(
    const double* __restrict__ acc, int base, double n, float* sh)
{
  __syncthreads();
  int t = threadIdx.x;
  if (t < 64) {
    double s = acc[base + 2 * t], q = acc[base + 2 * t + 1];
    for (int off = 32; off; off >>= 1) {
      s += __shfl_down(s, off, 64);
      q += __shfl_down(q, off, 64);
    }
    if (t == 0) {
      double var = (q - s * s / n) / (n - 1.0);
      *sh = var > 0.0 ? (float)(0.5 / var) : __builtin_inff();
    }
  }
  __syncthreads();
  return *sh;
}

// exp -> crelu(cb1) -> [0.81,0.9,1]/3 pool -> hi/lo (Kp=256) + xn   (dist2 = d^2)
__global__ __launch_bounds__(256) void l2_sfm(
    const float* __restrict__ dist2, const double* __restrict__ acc, double n,
    const float* __restrict__ cb, u16* __restrict__ Xhi, u16* __restrict__ Xlo,
    float* __restrict__ xn, int c0, int sdistc, int sXc, int sxnc)
{
  __shared__ float shinv;
  __shared__ float red[4];
  int zi = blockIdx.z, c = c0 + zi;
  dist2 += (size_t)zi * sdistc;
  Xhi += (size_t)zi * sXc; Xlo += (size_t)zi * sXc; xn += (size_t)zi * sxnc;
  float inv = block_inv_from_acc(acc + (size_t)c * ACC_TOTAL, ACC_L2, n, &shinv);
  int b = blockIdx.x, u = blockIdx.y, ch = threadIdx.x;
  float bias = cb[1];
  float v = 0.f;
  if (ch < 225) {
    const float av[3] = {0.81f, 0.9f, 1.0f};
    float a = 0.f;
#pragma unroll
    for (int vv = 0; vv < 3; ++vv) {
      float d2 = dist2[((size_t)b * 9 + u * 3 + vv) * 225 + ch];
      float e = fexp(-d2 * inv);
      e = (e >= bias) ? e : 0.f;
      a = fmaf(e, av[vv], a);
    }
    v = a * (1.f / 3.f);
  }
  size_t row = (size_t)b * 3 + u;
  u16 h = f2bf(v);
  u16 l = f2bf(v - bf2f(h));
  Xhi[row * 256 + ch] = h;
  Xlo[row * 256 + ch] = l;
  float p = v * v;
  for (int off = 32; off; off >>= 1) p += __shfl_down(p, off, 64);
  if ((ch & 63) == 0) red[ch >> 6] = p;
  __syncthreads();
  if (ch == 0) xn[row] = red[0] + red[1] + red[2] + red[3];
}

// exp -> crelu(cb2) -> [0.81,0.9,1]/3 pool -> hi/lo (Kp=640) + xn   (dist3 = d^2)
__global__ __launch_bounds__(256) void l3_sfm(
    const float* __restrict__ dist3, const double* __restrict__ acc, double n,
    const float* __restrict__ cb, u16* __restrict__ Xhi, u16* __restrict__ Xlo,
    float* __restrict__ xn, int c0, int sdistc, int sXc, int sxnc)
{
  __shared__ float shinv;
  __shared__ float red[4];
  int zi = blockIdx.y, c = c0 + zi;
  dist3 += (size_t)zi * sdistc;
  Xhi += (size_t)zi * sXc; Xlo += (size_t)zi * sXc; xn += (size_t)zi * sxnc;
  float inv = block_inv_from_acc(acc + (size_t)c * ACC_TOTAL, ACC_L3, n, &shinv);
  int b = blockIdx.x, t = threadIdx.x;
  float bias = cb[2];
  const float au[3] = {0.81f, 0.9f, 1.0f};
  float p = 0.f;
  for (int ch = t; ch < 640; ch += 256) {
    float v = 0.f;
    if (ch < 625) {
      float a = 0.f;
#pragma unroll
      for (int u = 0; u < 3; ++u) {
        float d2 = dist3[((size_t)b * 3 + u) * 625 + ch];
        float e = fexp(-d2 * inv);
        e = (e >= bias) ? e : 0.f;
        a = fmaf(e, au[u], a);
      }
      v = a * (1.f / 3.f);
    }
    u16 h = f2bf(v);
    u16 l = f2bf(v - bf2f(h));
    Xhi[(size_t)b * 640 + ch] = h;
    Xlo[(size_t)b * 640 + ch] = l;
    p = fmaf(v, v, p);
  }
  for (int off = 32; off; off >>= 1) p += __shfl_down(p, off, 64);
  if ((t & 63) == 0) red[t >> 6] = p;
  __syncthreads();
  if (t == 0) xn[b] = red[0] + red[1] + red[2] + red[3];
}

// L4 exp/crelu fused into FC; loops nc channels internally  (dist4 = d^2)
__global__ __launch_bounds__(128) void fc_acc(
    const float* __restrict__ dist4, const double* __restrict__ acc, double n,
    const float* __restrict__ cb, const float* __restrict__ fcw,
    const float* __restrict__ fcb, float* __restrict__ out,
    int c0, int nc, int sdistc)
{
  __shared__ float shinv;
  int b = blockIdx.x, t = threadIdx.x;
  float bias = cb[3];
  float p[10];
#pragma unroll
  for (int k = 0; k < 10; ++k) p[k] = 0.f;
  for (int zi = 0; zi < nc; ++zi) {
    int c = c0 + zi;
    float inv = block_inv_from_acc(acc + (size_t)c * ACC_TOTAL, ACC_L4, n, &shinv);
    const float* d4 = dist4 + (size_t)zi * sdistc;
    for (int j = t; j < 1225; j += 128) {
      float d2 = d4[(size_t)b * 1225 + j];
      float v = fexp(-d2 * inv);
      v = (v >= bias) ? v : 0.f;
#pragma unroll
      for (int k = 0; k < 10; ++k) p[k] = fmaf(v, fcw[k * 3675 + c * 1225 + j], p[k]);
    }
  }
#pragma unroll
  for (int k = 0; k < 10; ++k)
    for (int off = 32; off; off >>= 1) p[k] += __shfl_down(p[k], off, 64);
  __shared__ float red[2][10];
  int wave = t >> 6;
  if ((t & 63) == 0) {
#pragma unroll
    for (int k = 0; k < 10; ++k) red[wave][k] = p[k];
  }
  __syncthreads();
  if (t < 10) {
    float v = red[0][t] + red[1][t];
    if (c0 == 0) out[(size_t)b * 10 + t] = fcb[t] + v;
    else         out[(size_t)b * 10 + t] += v;
  }
}

extern "C" void kernel_launch(void* const* d_in, const int* in_sizes, int n_in,
                              void* d_out, int out_size, void* d_ws, size_t ws_size,
                              hipStream_t stream) {
  const float* x   = (const float*)d_in[0];
  const float* w1  = (const float*)d_in[1];
  const float* w2  = (const float*)d_in[2];
  const float* w3  = (const float*)d_in[3];
  const float* w4  = (const float*)d_in[4];
  const float* fcw = (const float*)d_in[5];
  const float* fcb = (const float*)d_in[6];
  const float* cb  = (const float*)d_in[7];
  float* out = (float*)d_out;
  const int B = in_sizes[0] / (3 * 28 * 28);   // 4096
  const int M2 = B * 9, M3 = B * 3;
  const int NB = B / 2;

  const size_t W2SZ = 256 * 128, W3SZ = 768 * 256, W4SZ = (size_t)1280 * 640;
  const size_t WTOT = 3 * (W2SZ + W3SZ + W4SZ);

  // tier 0: L1 batched (d1 x3) + L2-4 batched; tier 1: L1 serial, L2-4 batched;
  // tier 2: everything channel-serial.
  int tier;
  u16 *Xbase, *Whi, *Wlo, *W1h, *W1l;
  float *wn, *w1n, *xn, *inv36, *part;
  double* accd;
  float* Sf;
  for (tier = 0; tier < 3; ++tier) {
    size_t cur = 0;
    char* basep = (char*)d_ws;
    auto take = [&](size_t bytes) {
      void* r = basep + cur;
      cur = (cur + bytes + 255) & ~(size_t)255;
      return r;
    };
    int nc = (tier <= 1) ? 3 : 1;
    int ncL1 = (tier == 0) ? 3 : 1;
    size_t Ssz = (size_t)M2 * 225 * 4 * nc;
    size_t d1sz = (size_t)B * 3600 * 4 * ncL1;
    if (d1sz > Ssz) Ssz = d1sz;
    Sf = (float*)take(Ssz);
    Xbase = (u16*)take((size_t)M2 * 128 * 2 * 2 * nc);
    Whi = (u16*)take(WTOT * 2); Wlo = (u16*)take(WTOT * 2);
    W1h = (u16*)take(12288 * 2); W1l = (u16*)take(12288 * 2);
    wn  = (float*)take(3 * (256 + 768 + 1280) * 4);
    w1n = (float*)take(384 * 4);
    xn    = (float*)take((size_t)M2 * 4 * nc);
    inv36 = (float*)take(40 * 4 * ncL1);
    part  = (float*)take((size_t)72 * NB * 4 * ncL1);
    accd  = (double*)take(3 * ACC_TOTAL * 8);
    if (cur <= ws_size || tier == 2) break;
  }
  const int nc = (tier <= 1) ? 3 : 1;
  const bool batL1 = (tier == 0);

  const int sX2c   = (nc == 3) ? M2 * 128 * 2 : 0;
  const int sX3c   = (nc == 3) ? M3 * 256 * 2 : 0;
  const int sX4c   = (nc == 3) ? B * 640 * 2 : 0;
  const int sD2c   = (nc == 3) ? M2 * 225 : 0;
  const int sD3c   = (nc == 3) ? M3 * 625 : 0;
  const int sD4c   = (nc == 3) ? B * 1225 : 0;
  const int sXn2c  = (nc == 3) ? M2 : 0;
  const int sXn3c  = (nc == 3) ? M3 : 0;
  const int sXn4c  = (nc == 3) ? B : 0;
  const int sD1c   = batL1 ? B * 3600 : 0;
  const int sPartc = batL1 ? 72 * NB : 0;
  const int sInvL1 = batL1 ? 40 : 0;

  u16* x2hi = Xbase;   u16* x2lo = Xbase + (size_t)M2 * 128;
  u16* x3hi = Xbase;   u16* x3lo = Xbase + (size_t)M3 * 256;
  u16* x4hi = Xbase;   u16* x4lo = Xbase + (size_t)B * 640;
  u16* Whi2 = Whi;                 u16* Wlo2 = Wlo;                 float* wn2 = wn;
  u16* Whi3 = Whi + 3 * W2SZ;      u16* Wlo3 = Wlo + 3 * W2SZ;      float* wn3 = wn + 3 * 256;
  u16* Whi4 = Whi + 3 * (W2SZ + W3SZ); u16* Wlo4 = Wlo + 3 * (W2SZ + W3SZ);
  float* wn4 = wn + 3 * (256 + 768);

  // one prep dispatch: 9 zero-blocks + 384 + 768 + 2304 + 3840 w_prep blocks
  prep_all<<<9 + 384 + 768 + 2304 + 3840, 128, 0, stream>>>(
      w1, w2, w3, w4, W1h, W1l, Whi2, Wlo2, Whi3, Wlo3, Whi4, Wlo4,
      w1n, wn2, wn3, wn4, accd, 3 * ACC_TOTAL);

  for (int c0 = 0; c0 < 3; c0 += nc) {
    // ---- L1 ----
    if (batL1) {
      l1_gemm_d2<<<dim3(NB, 3), 256, 0, stream>>>(x, 0, W1h, W1l, w1n, Sf, sD1c,
                                                  part, sPartc, NB);
      l1_part_fin<<<dim3(36, 3), 256, 0, stream>>>(part, sPartc, inv36, sInvL1,
                                                   (double)B * 100.0, NB);
      l1_sfm_lite<<<dim3(B, 3), 128, 0, stream>>>(
          Sf, sD1c, inv36, sInvL1, cb, x2hi, x2lo, xn, sX2c, sXn2c);
    } else {
      for (int ci = 0; ci < nc; ++ci) {
        int c = c0 + ci;
        l1_gemm_d2<<<dim3(NB, 1), 256, 0, stream>>>(x, c, W1h, W1l, w1n, Sf, 0,
                                                    part, 0, NB);
        l1_part_fin<<<dim3(36, 1), 256, 0, stream>>>(part, 0, inv36, 0,
                                                     (double)B * 100.0, NB);
        l1_sfm_lite<<<dim3(B, 1), 128, 0, stream>>>(
            Sf, 0, inv36, 0, cb, x2hi + (size_t)ci * sX2c, x2lo + (size_t)ci * sX2c,
            xn + (size_t)ci * sXn2c, 0, 0);
      }
    }

    // L2: (M2 x 128) x (256 x 128) -> dist2 (M2 x 225)   grid 288x2x3
    gemm_dist_pipe<<<dim3(M2 / 128, 2, nc), 512, 0, stream>>>(
        x2hi, x2lo, Whi2, Wlo2, xn, wn2, Sf, 225, 128, accd, ACC_L2, c0,
        sX2c, (int)W2SZ, sXn2c, 256, sD2c);
    l2_sfm<<<dim3(B, 3, nc), 256, 0, stream>>>(
        Sf, accd, (double)M2 * 225.0, cb, x3hi, x3lo, xn, c0, sD2c, sX3c, sXn3c);

    // L3: (M3 x 256) x (768 x 256) -> dist3 (M3 x 625)   grid 96x6x3
    gemm_dist_pipe<<<dim3(M3 / 128, 6, nc), 512, 0, stream>>>(
        x3hi, x3lo, Whi3, Wlo3, xn, wn3, Sf, 625, 256, accd, ACC_L3, c0,
        sX3c, (int)W3SZ, sXn3c, 768, sD3c);
    l3_sfm<<<dim3(B, nc), 256, 0, stream>>>(
        Sf, accd, (double)M3 * 625.0, cb, x4hi, x4lo, xn, c0, sD3c, sX4c, sXn4c);

    // L4: (B x 640) x (1280 x 640) -> dist4 (B x 1225)   grid 32x10x3
    gemm_dist_pipe<<<dim3(B / 128, 10, nc), 512, 0, stream>>>(
        x4hi, x4lo, Whi4, Wlo4, xn, wn4, Sf, 1225, 640, accd, ACC_L4, c0,
        sX4c, (int)W4SZ, sXn4c, 1280, sD4c);
    fc_acc<<<B, 128, 0, stream>>>(
        Sf, accd, (double)B * 1225.0, cb, fcw, fcb, out, c0, nc, sD4c);
  }
}

// Round 11
// 475.383 us; speedup vs baseline: 1.1471x; 1.1147x over previous
//
#include <hip/hip_runtime.h>

// SOMNetwork forward. All four rbf/cdist layers via split-bf16 MFMA GEMM
// (hi/lo decomposition, 3 MFMAs/product).
// Round 19: REVERT to round-5 config (best verified 479.7us): 256x256-tile
// 8-wave 4-phase counted-vmcnt GEMM + scattered dword C-stores.
//   (r8 LDS-transpose store: -13%; r10 128^2 tile: -10% — both reverted.)
// NEW (T1): XCD-chunked block swizzle in gemm_dist_pipe. Consecutive dispatch
// ids share a W panel but round-robin across the 8 per-XCD L2s -> panels
// replicated 8x. Chunked bijection (n%8==0 for all grids here; identity
// fallback otherwise) gives each XCD a contiguous logical range.
// L1: d1 materialization; l1_gemm_d2 (LDS-transpose s/q reduce + cvt_pk
// hi/lo split) + l1_sfm_lite BW-bound re-read. prep_all merges zero+w_prep.
// Channels batched into grid z. Tiered ws fallback keeps old plans valid.

typedef unsigned short u16;
typedef short bf16x8 __attribute__((ext_vector_type(8)));
typedef float f32x4 __attribute__((ext_vector_type(4)));
typedef unsigned int u32;
typedef u32 u32x4 __attribute__((ext_vector_type(4)));

#define STRIPES 64
#define ACC_L2 0            // 64 stripes * 2 doubles per layer region
#define ACC_L3 128
#define ACC_L4 256
#define ACC_TOTAL 384

__device__ __forceinline__ u16 f2bf(float f) {
  unsigned int u = __float_as_uint(f);
  unsigned int r = (u + 0x7fffu + ((u >> 16) & 1u)) >> 16;
  return (u16)r;
}
__device__ __forceinline__ float bf2f(u16 h) {
  return __uint_as_float(((unsigned int)h) << 16);
}
// packed RNE bf16 convert: low16 = bf16(a), high16 = bf16(b)
__device__ __forceinline__ u32 cvtpk_bf16(float a, float b) {
  u32 r;
  asm("v_cvt_pk_bf16_f32 %0, %1, %2" : "=v"(r) : "v"(a), "v"(b));
  return r;
}
__device__ __forceinline__ float fexp(float x) { return __expf(x); }
__device__ __forceinline__ float fsqrt(float x) { return __builtin_amdgcn_sqrtf(x); }
__device__ __forceinline__ void gload16(const void* g, const void* l) {
  __builtin_amdgcn_global_load_lds(
      (const __attribute__((address_space(1))) unsigned int*)g,
      (__attribute__((address_space(3))) unsigned int*)l, 16, 0, 0);
}

// ---------------- prep_all: zero acc + all four w_preps in one dispatch ----------------
// block map: [0,9) zero acc; then L1 384, L2 768, L3 2304, L4 3840 blocks.
__global__ __launch_bounds__(128) void prep_all(
    const float* __restrict__ w1, const float* __restrict__ w2,
    const float* __restrict__ w3, const float* __restrict__ w4,
    u16* __restrict__ W1h, u16* __restrict__ W1l,
    u16* __restrict__ Whi2, u16* __restrict__ Wlo2,
    u16* __restrict__ Whi3, u16* __restrict__ Wlo3,
    u16* __restrict__ Whi4, u16* __restrict__ Wlo4,
    float* __restrict__ w1n, float* __restrict__ wn2,
    float* __restrict__ wn3, float* __restrict__ wn4,
    double* __restrict__ accd, int naccd)
{
  __shared__ float red[2];
  int bid = blockIdx.x, t = threadIdx.x;
  if (bid < 9) {
    int i = bid * 128 + t;
    if (i < naccd) accd[i] = 0.0;
    return;
  }
  bid -= 9;
  const float* W; u16 *hi, *lo; float* wn; int O, K, Opad, Kp;
  if (bid < 384)        { W = w1; hi = W1h;  lo = W1l;  wn = w1n; O = 100;  K = 25;  Opad = 128;  Kp = 32;  }
  else if (bid < 1152)  { bid -= 384;  W = w2; hi = Whi2; lo = Wlo2; wn = wn2; O = 225;  K = 100; Opad = 256;  Kp = 128; }
  else if (bid < 3456)  { bid -= 1152; W = w3; hi = Whi3; lo = Wlo3; wn = wn3; O = 625;  K = 225; Opad = 768;  Kp = 256; }
  else                  { bid -= 3456; W = w4; hi = Whi4; lo = Wlo4; wn = wn4; O = 1225; K = 625; Opad = 1280; Kp = 640; }
  int o = bid % Opad, cc = bid / Opad;
  const float* src = W + ((size_t)cc * O + o) * K;
  u16* dh = hi + ((size_t)cc * Opad + o) * Kp;
  u16* dl = lo + ((size_t)cc * Opad + o) * Kp;
  float p = 0.f;
  for (int k = t; k < Kp; k += 128) {
    float v = (o < O && k < K) ? src[k] : 0.f;
    u16 h = f2bf(v);
    u16 l = f2bf(v - bf2f(h));
    dh[k] = h; dl[k] = l;
    p = fmaf(v, v, p);
  }
  for (int off = 32; off; off >>= 1) p += __shfl_down(p, off, 64);
  if ((t & 63) == 0) red[t >> 6] = p;
  __syncthreads();
  if (t == 0) wn[(size_t)cc * Opad + o] = red[0] + red[1];
}

// ---------------- L1 GEMM pass: fused patch extraction + MFMA + d^2 store ----------------
__global__ __launch_bounds__(256) void l1_gemm_d2(
    const float* __restrict__ x, int c0,
    const u16* __restrict__ W1h, const u16* __restrict__ W1l,
    const float* __restrict__ w1n, float* __restrict__ dist1, int sD1c,
    float* __restrict__ part, int sPartc, int NBLK)
{
  __shared__ __align__(16) u16 sm[16384];   // patches+W (32 KB) -> reused as smf[2][36][66]
  __shared__ float img[1568];
  __shared__ float pnsm[512];
  __shared__ float pnloc[128];
  const int t = threadIdx.x;
  const int w = t >> 6, lane = t & 63;
  const int b0 = blockIdx.x * 2;
  const int zi = blockIdx.y, c = c0 + zi;
  const u16* Wh = W1h + (size_t)c * 4096;
  const u16* Wl = W1l + (size_t)c * 4096;
  const float* wn = w1n + (size_t)c * 128;
  dist1 += (size_t)zi * sD1c;
  part  += (size_t)zi * sPartc;

  {
    const int kk = (w & 3) * 8;
#pragma unroll
    for (int u = 0; u < 2; ++u) {
      const size_t gb = (size_t)(u * 64 + lane) * 32 + kk;
      const int ls = ((w & 3) * 128 + u * 64) * 8;
      gload16(Wh + gb, sm + 8192 + ls);
      gload16(Wl + gb, sm + 12288 + ls);
    }
  }
#pragma unroll
  for (int im = 0; im < 2; ++im) {
    if (t < 196)
      ((float4*)(img + im * 784))[t] =
          ((const float4*)(x + ((size_t)(b0 + im) * 3 + c) * 784))[t];
  }
  __syncthreads();
  for (int s = t; s < 512; s += 256) {
    int q = s >> 7, row = s & 127;
    int im = row >> 6, pr = row & 63;
    int pi = pr / 6, pj = pr - pi * 6;
    const float* ib = img + im * 784 + pi * 4 * 28 + pj * 4;
    float v[8]; float pn = 0.f;
#pragma unroll
    for (int e = 0; e < 8; ++e) {
      int k = q * 8 + e;
      float val = 0.f;
      if (pr < 36 && k < 25) { int r = k / 5, ss = k - r * 5; val = ib[r * 28 + ss]; }
      v[e] = val; pn = fmaf(val, val, pn);
    }
    u32x4 hp, lp;
#pragma unroll
    for (int e = 0; e < 4; ++e) {
      u32 h = cvtpk_bf16(v[2 * e], v[2 * e + 1]);
      float l0 = v[2 * e]     - __uint_as_float(h << 16);
      float l1 = v[2 * e + 1] - __uint_as_float(h & 0xffff0000u);
      hp[e] = h;
      lp[e] = cvtpk_bf16(l0, l1);
    }
    *(u32x4*)(sm + (q * 128 + row) * 8) = hp;
    *(u32x4*)(sm + 4096 + (q * 128 + row) * 8) = lp;
    pnsm[s] = pn;
  }
  asm volatile("s_waitcnt vmcnt(0)" ::: "memory");
  __syncthreads();
  if (t < 128) pnloc[t] = pnsm[t] + pnsm[128 + t] + pnsm[256 + t] + pnsm[384 + t];

  const int wr = w >> 1, wc = w & 1;
  const int q4 = lane >> 4, r16 = lane & 15;
  f32x4 accv[4][4];
#pragma unroll
  for (int i = 0; i < 4; ++i)
#pragma unroll
    for (int j = 0; j < 4; ++j) accv[i][j] = (f32x4){0.f, 0.f, 0.f, 0.f};

  bf16x8 Ah[4], Al[4], Bh[4], Bl[4];
#pragma unroll
  for (int i = 0; i < 4; ++i) {
    int ao = (q4 * 128 + wr * 64 + i * 16 + r16) * 8;
    int bo = (q4 * 128 + wc * 64 + i * 16 + r16) * 8;
    Ah[i] = *(const bf16x8*)(sm + ao);
    Al[i] = *(const bf16x8*)(sm + 4096 + ao);
    Bh[i] = *(const bf16x8*)(sm + 8192 + bo);
    Bl[i] = *(const bf16x8*)(sm + 12288 + bo);
  }
#pragma unroll
  for (int j = 0; j < 4; ++j) {
#pragma unroll
    for (int i = 0; i < 4; ++i)
      accv[i][j] = __builtin_amdgcn_mfma_f32_16x16x32_bf16(Ah[i], Bh[j], accv[i][j], 0, 0, 0);
#pragma unroll
    for (int i = 0; i < 4; ++i)
      accv[i][j] = __builtin_amdgcn_mfma_f32_16x16x32_bf16(Al[i], Bh[j], accv[i][j], 0, 0, 0);
#pragma unroll
    for (int i = 0; i < 4; ++i)
      accv[i][j] = __builtin_amdgcn_mfma_f32_16x16x32_bf16(Ah[i], Bl[j], accv[i][j], 0, 0, 0);
  }
  __syncthreads();   // all fragment reads of sm done -> safe to reuse as smf

  // s/q partials via LDS transpose: smf[kind][pos][w*16+r16], stride 66.
  float* smf = (float*)sm;
  int colv[4]; float wnv[4];
#pragma unroll
  for (int j = 0; j < 4; ++j) {
    colv[j] = wc * 64 + j * 16 + r16;
    wnv[j] = (colv[j] < 100) ? wn[colv[j]] : 0.f;
  }
#pragma unroll
  for (int i = 0; i < 4; ++i) {
#pragma unroll
    for (int r = 0; r < 4; ++r) {
      int pos = i * 16 + q4 * 4 + r;
      if (pos < 36) {           // uniform within each 16-lane (r16) group
        float pn = pnloc[wr * 64 + pos];
        float* drow = dist1 + ((size_t)(b0 + wr) * 36 + pos) * 100;
        float sl = 0.f, ql = 0.f;
#pragma unroll
        for (int j = 0; j < 4; ++j) {
          if (colv[j] < 100) {
            float d2 = pn + wnv[j] - 2.f * accv[i][j][r];
            float d2c = fmaxf(d2, 0.f) + 1e-12f;
            drow[colv[j]] = d2c;
            sl += fsqrt(d2c); ql += d2c;
          }
        }
        smf[pos * 66 + w * 16 + r16] = sl;
        smf[(36 + pos) * 66 + w * 16 + r16] = ql;
      }
    }
  }
  __syncthreads();
  if (t < 72) {
    const float* row = smf + (size_t)t * 66;
    float v0 = 0.f;
#pragma unroll
    for (int k = 0; k < 64; ++k) v0 += row[k];
    part[(size_t)t * NBLK + blockIdx.x] = v0;
  }
}

// ---------------- L1 partial finish: per-block partials -> inv36 ----------------
__global__ __launch_bounds__(256) void l1_part_fin(
    const float* __restrict__ part, int sPartc, float* __restrict__ inv36, int sInvc,
    double n, int NBLK)
{
  __shared__ double sh[8];
  int pos = blockIdx.x, zi = blockIdx.y, t = threadIdx.x;
  part += (size_t)zi * sPartc; inv36 += (size_t)zi * sInvc;
  double s = 0.0, q = 0.0;
  for (int b = t; b < NBLK; b += 256) {
    s += part[(size_t)pos * NBLK + b];
    q += part[(size_t)(36 + pos) * NBLK + b];
  }
  for (int off = 32; off; off >>= 1) {
    s += __shfl_down(s, off, 64);
    q += __shfl_down(q, off, 64);
  }
  if ((t & 63) == 0) { sh[(t >> 6) * 2] = s; sh[(t >> 6) * 2 + 1] = q; }
  __syncthreads();
  if (t == 0) {
    s = sh[0] + sh[2] + sh[4] + sh[6];
    q = sh[1] + sh[3] + sh[5] + sh[7];
    double var = (q - s * s / n) / (n - 1.0);
    inv36[pos] = var > 0.0 ? (float)(0.5 / var) : __builtin_inff();
  }
}

// ---------------- L1 sfm: d^2 -> exp/crelu -> 2x2 alpha-pool -> X hi/lo + xn ----------------
__global__ __launch_bounds__(128) void l1_sfm_lite(
    const float* __restrict__ d1, int sD1c,
    const float* __restrict__ inv36, int sInvc, const float* __restrict__ cb,
    u16* __restrict__ Xhi, u16* __restrict__ Xlo, float* __restrict__ xn,
    int sXc, int sxnc)
{
  __shared__ float inv_s[36];
  __shared__ float xnsm[9][2];
  int b = blockIdx.x, zi = blockIdx.y, t = threadIdx.x;
  d1 += (size_t)zi * sD1c; inv36 += (size_t)zi * sInvc;
  Xhi += (size_t)zi * sXc; Xlo += (size_t)zi * sXc; xn += (size_t)zi * sxnc;
  if (t < 36) inv_s[t] = inv36[t];
  __syncthreads();
  const float* db = d1 + (size_t)b * 3600;
  float bias = cb[0];
  int wv = t >> 6;
#pragma unroll
  for (int IJ = 0; IJ < 9; ++IJ) {
    const int I = IJ / 3, J = IJ - I * 3;
    const int p00 = 12 * I + 2 * J;
    float v = 0.f;
    if (t < 100) {
      float e00 = fexp(-db[p00 * 100 + t] * inv_s[p00]);
      float e01 = fexp(-db[(p00 + 1) * 100 + t] * inv_s[p00 + 1]);
      float e10 = fexp(-db[(p00 + 6) * 100 + t] * inv_s[p00 + 6]);
      float e11 = fexp(-db[(p00 + 7) * 100 + t] * inv_s[p00 + 7]);
      e00 = (e00 >= bias) ? e00 : 0.f;
      e01 = (e01 >= bias) ? e01 : 0.f;
      e10 = (e10 >= bias) ? e10 : 0.f;
      e11 = (e11 >= bias) ? e11 : 0.f;
      v = 0.25f * (fmaf(0.729f, e00, 0.81f * e01) + fmaf(0.9f, e10, e11));
    }
    size_t xrow = (size_t)b * 9 + IJ;
    u16 h = f2bf(v);
    u16 l = f2bf(v - bf2f(h));
    Xhi[xrow * 128 + t] = h;
    Xlo[xrow * 128 + t] = l;
    float p = v * v;
    for (int off = 32; off; off >>= 1) p += __shfl_down(p, off, 64);
    if ((t & 63) == 0) xnsm[IJ][wv] = p;
  }
  __syncthreads();
  if (t < 9) xn[(size_t)b * 9 + t] = xnsm[t][0] + xnsm[t][1];
}

// ---------------- 256x256-tile 8-wave 4-phase pipelined split-bf16 MFMA cdist GEMM ----------------
// Per K-step (BK=32): 4 phases over j-pairs. Stage issue per tile, in order:
// ph0 -> Xu0 (hi,lo), ph1 -> Xu1, ph2 -> Wu0, ph3 -> Wu1  (2 loads/phase).
// Waits: ph0 vmcnt(2), ph2 vmcnt(4) (vmcnt(0) at last step) — never drains
// mid-loop. Every phase: barrier -> ds_read -> stage-issue -> lgkmcnt(0)+
// sched_barrier -> setprio(1) 24 MFMA setprio(0). FP order per accv[i][j]
// unchanged (hh, lh, hl; i ascending).
// Round 19: XCD-chunked block swizzle (T1). Raw dispatch id d -> logical
// tile (d%8)*(n/8) + d/8 when n%8==0 (identity otherwise): each XCD gets a
// contiguous logical chunk -> shared X/W panels stay in one L2.
__global__ __launch_bounds__(512, 2) void gemm_dist_pipe(
    const u16* __restrict__ Xhi, const u16* __restrict__ Xlo,
    const u16* __restrict__ Whi, const u16* __restrict__ Wlo,
    const float* __restrict__ xn, const float* __restrict__ wn,
    float* __restrict__ dist, int O, int Kp,
    double* __restrict__ acc, int accbase, int c0,
    int sXc, int sWc, int sxnc, int swnc, int sdistc)
{
  __shared__ __align__(16) u16 sm[65536];   // 128 KB: buffers at 0 and 32768
  // ---- XCD-chunked swizzle (bijective when n%8==0) ----
  const int gx = gridDim.x, gy = gridDim.y;
  const int n = gx * gy * gridDim.z;
  int d = blockIdx.x + gx * (blockIdx.y + gy * blockIdx.z);
  int logical = (n & 7) ? d : ((d & 7) * (n >> 3) + (d >> 3));
  const int bz = logical / (gx * gy);
  const int rem = logical - bz * gx * gy;
  const int by = rem / gx;
  const int bx = rem - by * gx;

  int zi = bz, c = c0 + zi;
  Xhi += (size_t)zi * sXc; Xlo += (size_t)zi * sXc;
  Whi += (size_t)c * sWc;  Wlo += (size_t)c * sWc;
  xn += (size_t)zi * sxnc; wn += (size_t)c * swnc;
  dist += (size_t)zi * sdistc;
  acc += (size_t)c * ACC_TOTAL;

  const int t = threadIdx.x;
  const int w = t >> 6, lane = t & 63;
  const int wr = w >> 1, wc = w & 1;
  const int sq = w & 3, half = w >> 2;
  const int m0 = bx * 256, o0 = by * 256;
  const int q4 = lane >> 4, r16 = lane & 15;
  const int nsteps = Kp / 32;

  f32x4 accv[4][8];
#pragma unroll
  for (int i = 0; i < 4; ++i)
#pragma unroll
    for (int j = 0; j < 8; ++j) accv[i][j] = (f32x4){0.f, 0.f, 0.f, 0.f};

  // one X u-granule (hi+lo) = 2 loads
  auto stageA_u = [&](int buf, int ks, int u) {
    const int kk = ks * 32 + sq * 8;
    u16* base = sm + buf * 32768;
    const int row = half * 128 + u * 64 + lane;
    const size_t ga = (size_t)(m0 + row) * Kp + kk;
    const int ls = (sq * 256 + half * 128 + u * 64) * 8;
    gload16(Xhi + ga, base + ls);
    gload16(Xlo + ga, base + 8192 + ls);
  };
  // one W u-granule (hi+lo) = 2 loads
  auto stageB_u = [&](int buf, int ks, int u) {
    const int kk = ks * 32 + sq * 8;
    u16* base = sm + buf * 32768;
    const int row = half * 128 + u * 64 + lane;
    const size_t gb = (size_t)(o0 + row) * Kp + kk;
    const int ls = (sq * 256 + half * 128 + u * 64) * 8;
    gload16(Whi + gb, base + 16384 + ls);
    gload16(Wlo + gb, base + 24576 + ls);
  };

  // prologue: tile 0, issue order [Xu0, Xu1, Wu0, Wu1] = loads 1..8
  stageA_u(0, 0, 0); stageA_u(0, 0, 1);
  stageB_u(0, 0, 0); stageB_u(0, 0, 1);

  for (int ks = 0; ks < nsteps; ++ks) {
    const u16* base = sm + (ks & 1) * 32768;
    const int nb = (ks + 1) & 1;
    const bool more = (ks + 1 < nsteps);
    bf16x8 Ah[4], Al[4];

#pragma unroll
    for (int ph = 0; ph < 4; ++ph) {
      if (ph == 0) {
        asm volatile("s_waitcnt vmcnt(2)\n\ts_barrier" ::: "memory");
      } else if (ph == 2) {
        if (more) asm volatile("s_waitcnt vmcnt(4)\n\ts_barrier" ::: "memory");
        else      asm volatile("s_waitcnt vmcnt(0)\n\ts_barrier" ::: "memory");
      } else {
        __builtin_amdgcn_s_barrier();
      }
      if (ph == 0) {
#pragma unroll
        for (int i = 0; i < 4; ++i) {
          int ao = (q4 * 256 + wr * 64 + i * 16 + r16) * 8;
          Ah[i] = *(const bf16x8*)(base + ao);
          Al[i] = *(const bf16x8*)(base + 8192 + ao);
        }
      }
      const int j0 = ph * 2;
      int bo0 = (q4 * 256 + wc * 128 + j0 * 16 + r16) * 8;
      int bo1 = (q4 * 256 + wc * 128 + (j0 + 1) * 16 + r16) * 8;
      bf16x8 Bh0 = *(const bf16x8*)(base + 16384 + bo0);
      bf16x8 Bl0 = *(const bf16x8*)(base + 24576 + bo0);
      bf16x8 Bh1 = *(const bf16x8*)(base + 16384 + bo1);
      bf16x8 Bl1 = *(const bf16x8*)(base + 24576 + bo1);
      if (more) {
        if (ph == 0)      stageA_u(nb, ks + 1, 0);
        else if (ph == 1) stageA_u(nb, ks + 1, 1);
        else if (ph == 2) stageB_u(nb, ks + 1, 0);
        else              stageB_u(nb, ks + 1, 1);
      }
      asm volatile("s_waitcnt lgkmcnt(0)" ::: "memory");
      __builtin_amdgcn_sched_barrier(0);
      __builtin_amdgcn_s_setprio(1);
#pragma unroll
      for (int i = 0; i < 4; ++i)
        accv[i][j0] = __builtin_amdgcn_mfma_f32_16x16x32_bf16(Ah[i], Bh0, accv[i][j0], 0, 0, 0);
#pragma unroll
      for (int i = 0; i < 4; ++i)
        accv[i][j0] = __builtin_amdgcn_mfma_f32_16x16x32_bf16(Al[i], Bh0, accv[i][j0], 0, 0, 0);
#pragma unroll
      for (int i = 0; i < 4; ++i)
        accv[i][j0] = __builtin_amdgcn_mfma_f32_16x16x32_bf16(Ah[i], Bl0, accv[i][j0], 0, 0, 0);
#pragma unroll
      for (int i = 0; i < 4; ++i)
        accv[i][j0 + 1] = __builtin_amdgcn_mfma_f32_16x16x32_bf16(Ah[i], Bh1, accv[i][j0 + 1], 0, 0, 0);
#pragma unroll
      for (int i = 0; i < 4; ++i)
        accv[i][j0 + 1] = __builtin_amdgcn_mfma_f32_16x16x32_bf16(Al[i], Bh1, accv[i][j0 + 1], 0, 0, 0);
#pragma unroll
      for (int i = 0; i < 4; ++i)
        accv[i][j0 + 1] = __builtin_amdgcn_mfma_f32_16x16x32_bf16(Ah[i], Bl1, accv[i][j0 + 1], 0, 0, 0);
      __builtin_amdgcn_s_setprio(0);
    }
  }

  double s = 0.0, qd = 0.0;
#pragma unroll
  for (int i = 0; i < 4; ++i) {
    const int mb = m0 + wr * 64 + i * 16 + q4 * 4;
    float xnv[4];
#pragma unroll
    for (int r = 0; r < 4; ++r) xnv[r] = xn[mb + r];
    float sf = 0.f, qf = 0.f;
#pragma unroll
    for (int j = 0; j < 8; ++j) {
      const int o = o0 + wc * 128 + j * 16 + r16;
      if (o < O) {
        const float wnv = wn[o];
#pragma unroll
        for (int r = 0; r < 4; ++r) {
          float d2 = xnv[r] + wnv - 2.f * accv[i][j][r];
          float d2c = fmaxf(d2, 0.f) + 1e-12f;
          dist[(size_t)(mb + r) * O + o] = d2c;
          sf += fsqrt(d2c); qf += d2c;
        }
      }
    }
    s += sf; qd += qf;
  }
  for (int off = 32; off; off >>= 1) {
    s += __shfl_down(s, off, 64);
    qd += __shfl_down(qd, off, 64);
  }
  // use the LDS buffer NOT read by the final K-step (nsteps even -> buffer 0)
  double* redsm = (double*)(sm + (nsteps & 1) * 32768);
  if (lane == 0) { redsm[w * 2] = s; redsm[w * 2 + 1] = qd; }
  __syncthreads();
  if (t == 0) {
    s = 0.0; qd = 0.0;
#pragma unroll
    for (int ww = 0; ww < 8; ++ww) { s += redsm[ww * 2]; qd += redsm[ww * 2 + 1]; }
    int stripe = (bx + by * gx) & (STRIPES - 1);
    atomicAdd(&acc[accbase + stripe * 2], s);
    atomicAdd(&acc[accbase + stripe * 2 + 1], qd);
  }
}

__device__ __forceinline__ float block_inv_from_acc(
    const double* __restrict__ acc, int base, double n, float* sh)
{
  __syncthreads();
  int t = threadIdx.x;
  if (t < 64) {
    double s = acc[base + 2 * t], q = acc[base + 2 * t + 1];
    for (int off = 32; off; off >>= 1) {
      s += __shfl_down(s, off, 64);
      q += __shfl_down(q, off, 64);
    }
    if (t == 0) {
      double var = (q - s * s / n) / (n - 1.0);
      *sh = var > 0.0 ? (float)(0.5 / var) : __builtin_inff();
    }
  }
  __syncthreads();
  return *sh;
}

// exp -> crelu(cb1) -> [0.81,0.9,1]/3 pool -> hi/lo (Kp=256) + xn   (dist2 = d^2)
__global__ __launch_bounds__(256) void l2_sfm(
    const float* __restrict__ dist2, const double* __restrict__ acc, double n,
    const float* __restrict__ cb, u16* __restrict__ Xhi, u16* __restrict__ Xlo,
    float* __restrict__ xn, int c0, int sdistc, int sXc, int sxnc)
{
  __shared__ float shinv;
  __shared__ float red[4];
  int zi = blockIdx.z, c = c0 + zi;
  dist2 += (size_t)zi * sdistc;
  Xhi += (size_t)zi * sXc; Xlo += (size_t)zi * sXc; xn += (size_t)zi * sxnc;
  float inv = block_inv_from_acc(acc + (size_t)c * ACC_TOTAL, ACC_L2, n, &shinv);
  int b = blockIdx.x, u = blockIdx.y, ch = threadIdx.x;
  float bias = cb[1];
  float v = 0.f;
  if (ch < 225) {
    const float av[3] = {0.81f, 0.9f, 1.0f};
    float a = 0.f;
#pragma unroll
    for (int vv = 0; vv < 3; ++vv) {
      float d2 = dist2[((size_t)b * 9 + u * 3 + vv) * 225 + ch];
      float e = fexp(-d2 * inv);
      e = (e >= bias) ? e : 0.f;
      a = fmaf(e, av[vv], a);
    }
    v = a * (1.f / 3.f);
  }
  size_t row = (size_t)b * 3 + u;
  u16 h = f2bf(v);
  u16 l = f2bf(v - bf2f(h));
  Xhi[row * 256 + ch] = h;
  Xlo[row * 256 + ch] = l;
  float p = v * v;
  for (int off = 32; off; off >>= 1) p += __shfl_down(p, off, 64);
  if ((ch & 63) == 0) red[ch >> 6] = p;
  __syncthreads();
  if (ch == 0) xn[row] = red[0] + red[1] + red[2] + red[3];
}

// exp -> crelu(cb2) -> [0.81,0.9,1]/3 pool -> hi/lo (Kp=640) + xn   (dist3 = d^2)
__global__ __launch_bounds__(256) void l3_sfm(
    const float* __restrict__ dist3, const double* __restrict__ acc, double n,
    const float* __restrict__ cb, u16* __restrict__ Xhi, u16* __restrict__ Xlo,
    float* __restrict__ xn, int c0, int sdistc, int sXc, int sxnc)
{
  __shared__ float shinv;
  __shared__ float red[4];
  int zi = blockIdx.y, c = c0 + zi;
  dist3 += (size_t)zi * sdistc;
  Xhi += (size_t)zi * sXc; Xlo += (size_t)zi * sXc; xn += (size_t)zi * sxnc;
  float inv = block_inv_from_acc(acc + (size_t)c * ACC_TOTAL, ACC_L3, n, &shinv);
  int b = blockIdx.x, t = threadIdx.x;
  float bias = cb[2];
  const float au[3] = {0.81f, 0.9f, 1.0f};
  float p = 0.f;
  for (int ch = t; ch < 640; ch += 256) {
    float v = 0.f;
    if (ch < 625) {
      float a = 0.f;
#pragma unroll
      for (int u = 0; u < 3; ++u) {
        float d2 = dist3[((size_t)b * 3 + u) * 625 + ch];
        float e = fexp(-d2 * inv);
        e = (e >= bias) ? e : 0.f;
        a = fmaf(e, au[u], a);
      }
      v = a * (1.f / 3.f);
    }
    u16 h = f2bf(v);
    u16 l = f2bf(v - bf2f(h));
    Xhi[(size_t)b * 640 + ch] = h;
    Xlo[(size_t)b * 640 + ch] = l;
    p = fmaf(v, v, p);
  }
  for (int off = 32; off; off >>= 1) p += __shfl_down(p, off, 64);
  if ((t & 63) == 0) red[t >> 6] = p;
  __syncthreads();
  if (t == 0) xn[b] = red[0] + red[1] + red[2] + red[3];
}

// L4 exp/crelu fused into FC; loops nc channels internally  (dist4 = d^2)
__global__ __launch_bounds__(128) void fc_acc(
    const float* __restrict__ dist4, const double* __restrict__ acc, double n,
    const float* __restrict__ cb, const float* __restrict__ fcw,
    const float* __restrict__ fcb, float* __restrict__ out,
    int c0, int nc, int sdistc)
{
  __shared__ float shinv;
  int b = blockIdx.x, t = threadIdx.x;
  float bias = cb[3];
  float p[10];
#pragma unroll
  for (int k = 0; k < 10; ++k) p[k] = 0.f;
  for (int zi = 0; zi < nc; ++zi) {
    int c = c0 + zi;
    float inv = block_inv_from_acc(acc + (size_t)c * ACC_TOTAL, ACC_L4, n, &shinv);
    const float* d4 = dist4 + (size_t)zi * sdistc;
    for (int j = t; j < 1225; j += 128) {
      float d2 = d4[(size_t)b * 1225 + j];
      float v = fexp(-d2 * inv);
      v = (v >= bias) ? v : 0.f;
#pragma unroll
      for (int k = 0; k < 10; ++k) p[k] = fmaf(v, fcw[k * 3675 + c * 1225 + j], p[k]);
    }
  }
#pragma unroll
  for (int k = 0; k < 10; ++k)
    for (int off = 32; off; off >>= 1) p[k] += __shfl_down(p[k], off, 64);
  __shared__ float red[2][10];
  int wave = t >> 6;
  if ((t & 63) == 0) {
#pragma unroll
    for (int k = 0; k < 10; ++k) red[wave][k] = p[k];
  }
  __syncthreads();
  if (t < 10) {
    float v = red[0][t] + red[1][t];
    if (c0 == 0) out[(size_t)b * 10 + t] = fcb[t] + v;
    else         out[(size_t)b * 10 + t] += v;
  }
}

extern "C" void kernel_launch(void* const* d_in, const int* in_sizes, int n_in,
                              void* d_out, int out_size, void* d_ws, size_t ws_size,
                              hipStream_t stream) {
  const float* x   = (const float*)d_in[0];
  const float* w1  = (const float*)d_in[1];
  const float* w2  = (const float*)d_in[2];
  const float* w3  = (const float*)d_in[3];
  const float* w4  = (const float*)d_in[4];
  const float* fcw = (const float*)d_in[5];
  const float* fcb = (const float*)d_in[6];
  const float* cb  = (const float*)d_in[7];
  float* out = (float*)d_out;
  const int B = in_sizes[0] / (3 * 28 * 28);   // 4096
  const int M2 = B * 9, M3 = B * 3;
  const int NB = B / 2;

  const size_t W2SZ = 256 * 128, W3SZ = 768 * 256, W4SZ = (size_t)1280 * 640;
  const size_t WTOT = 3 * (W2SZ + W3SZ + W4SZ);

  // tier 0: L1 batched (d1 x3) + L2-4 batched; tier 1: L1 serial, L2-4 batched;
  // tier 2: everything channel-serial.
  int tier;
  u16 *Xbase, *Whi, *Wlo, *W1h, *W1l;
  float *wn, *w1n, *xn, *inv36, *part;
  double* accd;
  float* Sf;
  for (tier = 0; tier < 3; ++tier) {
    size_t cur = 0;
    char* basep = (char*)d_ws;
    auto take = [&](size_t bytes) {
      void* r = basep + cur;
      cur = (cur + bytes + 255) & ~(size_t)255;
      return r;
    };
    int nc = (tier <= 1) ? 3 : 1;
    int ncL1 = (tier == 0) ? 3 : 1;
    size_t Ssz = (size_t)M2 * 225 * 4 * nc;
    size_t d1sz = (size_t)B * 3600 * 4 * ncL1;
    if (d1sz > Ssz) Ssz = d1sz;
    Sf = (float*)take(Ssz);
    Xbase = (u16*)take((size_t)M2 * 128 * 2 * 2 * nc);
    Whi = (u16*)take(WTOT * 2); Wlo = (u16*)take(WTOT * 2);
    W1h = (u16*)take(12288 * 2); W1l = (u16*)take(12288 * 2);
    wn  = (float*)take(3 * (256 + 768 + 1280) * 4);
    w1n = (float*)take(384 * 4);
    xn    = (float*)take((size_t)M2 * 4 * nc);
    inv36 = (float*)take(40 * 4 * ncL1);
    part  = (float*)take((size_t)72 * NB * 4 * ncL1);
    accd  = (double*)take(3 * ACC_TOTAL * 8);
    if (cur <= ws_size || tier == 2) break;
  }
  const int nc = (tier <= 1) ? 3 : 1;
  const bool batL1 = (tier == 0);

  const int sX2c   = (nc == 3) ? M2 * 128 * 2 : 0;
  const int sX3c   = (nc == 3) ? M3 * 256 * 2 : 0;
  const int sX4c   = (nc == 3) ? B * 640 * 2 : 0;
  const int sD2c   = (nc == 3) ? M2 * 225 : 0;
  const int sD3c   = (nc == 3) ? M3 * 625 : 0;
  const int sD4c   = (nc == 3) ? B * 1225 : 0;
  const int sXn2c  = (nc == 3) ? M2 : 0;
  const int sXn3c  = (nc == 3) ? M3 : 0;
  const int sXn4c  = (nc == 3) ? B : 0;
  const int sD1c   = batL1 ? B * 3600 : 0;
  const int sPartc = batL1 ? 72 * NB : 0;
  const int sInvL1 = batL1 ? 40 : 0;

  u16* x2hi = Xbase;   u16* x2lo = Xbase + (size_t)M2 * 128;
  u16* x3hi = Xbase;   u16* x3lo = Xbase + (size_t)M3 * 256;
  u16* x4hi = Xbase;   u16* x4lo = Xbase + (size_t)B * 640;
  u16* Whi2 = Whi;                 u16* Wlo2 = Wlo;                 float* wn2 = wn;
  u16* Whi3 = Whi + 3 * W2SZ;      u16* Wlo3 = Wlo + 3 * W2SZ;      float* wn3 = wn + 3 * 256;
  u16* Whi4 = Whi + 3 * (W2SZ + W3SZ); u16* Wlo4 = Wlo + 3 * (W2SZ + W3SZ);
  float* wn4 = wn + 3 * (256 + 768);

  // one prep dispatch: 9 zero-blocks + 384 + 768 + 2304 + 3840 w_prep blocks
  prep_all<<<9 + 384 + 768 + 2304 + 3840, 128, 0, stream>>>(
      w1, w2, w3, w4, W1h, W1l, Whi2, Wlo2, Whi3, Wlo3, Whi4, Wlo4,
      w1n, wn2, wn3, wn4, accd, 3 * ACC_TOTAL);

  for (int c0 = 0; c0 < 3; c0 += nc) {
    // ---- L1 ----
    if (batL1) {
      l1_gemm_d2<<<dim3(NB, 3), 256, 0, stream>>>(x, 0, W1h, W1l, w1n, Sf, sD1c,
                                                  part, sPartc, NB);
      l1_part_fin<<<dim3(36, 3), 256, 0, stream>>>(part, sPartc, inv36, sInvL1,
                                                   (double)B * 100.0, NB);
      l1_sfm_lite<<<dim3(B, 3), 128, 0, stream>>>(
          Sf, sD1c, inv36, sInvL1, cb, x2hi, x2lo, xn, sX2c, sXn2c);
    } else {
      for (int ci = 0; ci < nc; ++ci) {
        int c = c0 + ci;
        l1_gemm_d2<<<dim3(NB, 1), 256, 0, stream>>>(x, c, W1h, W1l, w1n, Sf, 0,
                                                    part, 0, NB);
        l1_part_fin<<<dim3(36, 1), 256, 0, stream>>>(part, 0, inv36, 0,
                                                     (double)B * 100.0, NB);
        l1_sfm_lite<<<dim3(B, 1), 128, 0, stream>>>(
            Sf, 0, inv36, 0, cb, x2hi + (size_t)ci * sX2c, x2lo + (size_t)ci * sX2c,
            xn + (size_t)ci * sXn2c, 0, 0);
      }
    }

    // L2: (M2 x 128) x (256 x 128) -> dist2 (M2 x 225)
    gemm_dist_pipe<<<dim3(M2 / 256, 1, nc), 512, 0, stream>>>(
        x2hi, x2lo, Whi2, Wlo2, xn, wn2, Sf, 225, 128, accd, ACC_L2, c0,
        sX2c, (int)W2SZ, sXn2c, 256, sD2c);
    l2_sfm<<<dim3(B, 3, nc), 256, 0, stream>>>(
        Sf, accd, (double)M2 * 225.0, cb, x3hi, x3lo, xn, c0, sD2c, sX3c, sXn3c);

    // L3: (M3 x 256) x (768 x 256) -> dist3 (M3 x 625)
    gemm_dist_pipe<<<dim3(M3 / 256, 3, nc), 512, 0, stream>>>(
        x3hi, x3lo, Whi3, Wlo3, xn, wn3, Sf, 625, 256, accd, ACC_L3, c0,
        sX3c, (int)W3SZ, sXn3c, 768, sD3c);
    l3_sfm<<<dim3(B, nc), 256, 0, stream>>>(
        Sf, accd, (double)M3 * 625.0, cb, x4hi, x4lo, xn, c0, sD3c, sX4c, sXn4c);

    // L4: (B x 640) x (1280 x 640) -> dist4 (B x 1225)
    gemm_dist_pipe<<<dim3(B / 256, 5, nc), 512, 0, stream>>>(
        x4hi, x4lo, Whi4, Wlo4, xn, wn4, Sf, 1225, 640, accd, ACC_L4, c0,
        sX4c, (int)W4SZ, sXn4c, 1280, sD4c);
    fc_acc<<<B, 128, 0, stream>>>(
        Sf, accd, (double)B * 1225.0, cb, fcw, fcb, out, c0, nc, sD4c);
  }
}